// Round 1
// baseline (6232.507 us; speedup 1.0000x reference)
//
#include <hip/hip_runtime.h>
#include <cfloat>
#include <cstdint>

#define NPTS 131072
#define NB 64
#define MAXPB 2560
#define MT 128
#define TD 768

// ---------------------------------------------------------------------------
// Per-point: LayerNorm(4) -> 4x64 relu -> 64x64 relu -> X96 = [feat32, sp64]
// sel != nullptr: gather variant (p = sel[r], p<0 -> zero row)
// ---------------------------------------------------------------------------
__global__ __launch_bounds__(256) void k_x96(
    const float* __restrict__ coords, const float* __restrict__ feats,
    const float* __restrict__ times,
    const float* __restrict__ ln_g, const float* __restrict__ ln_b,
    const float* __restrict__ sw1, const float* __restrict__ sb1,
    const float* __restrict__ sw2, const float* __restrict__ sb2,
    const int* __restrict__ sel, int p0, int M, float* __restrict__ X96)
{
    __shared__ float w1[256], w2[4096], b1[64], b2[64];
    int t = threadIdx.x;
    w1[t] = sw1[t];
    for (int i = t; i < 4096; i += 256) w2[i] = sw2[i];
    if (t < 64) { b1[t] = sb1[t]; b2[t] = sb2[t]; }
    __syncthreads();

    int r = blockIdx.x * 256 + t;
    if (r >= M) return;
    int p = sel ? sel[r] : (p0 + r);
    float* out = X96 + (size_t)r * 96;
    if (p < 0) {
        for (int j = 0; j < 96; j += 4) *(float4*)(out + j) = make_float4(0.f,0.f,0.f,0.f);
        return;
    }
    float x0 = coords[(size_t)p*3+0], x1 = coords[(size_t)p*3+1];
    float x2 = coords[(size_t)p*3+2], x3 = times[p];
    float mu = 0.25f*(x0+x1+x2+x3);
    float d0 = x0-mu, d1 = x1-mu, d2 = x2-mu, d3 = x3-mu;
    float var = 0.25f*(d0*d0+d1*d1+d2*d2+d3*d3);
    float inv = 1.0f / sqrtf(var + 1e-5f);
    float xn0 = d0*inv*ln_g[0]+ln_b[0];
    float xn1 = d1*inv*ln_g[1]+ln_b[1];
    float xn2 = d2*inv*ln_g[2]+ln_b[2];
    float xn3 = d3*inv*ln_g[3]+ln_b[3];

    float s1[64];
    #pragma unroll
    for (int j = 0; j < 64; ++j) {
        float a = b1[j];
        a = fmaf(xn0, w1[j],       a);
        a = fmaf(xn1, w1[64 + j],  a);
        a = fmaf(xn2, w1[128 + j], a);
        a = fmaf(xn3, w1[192 + j], a);
        s1[j] = fmaxf(a, 0.f);
    }
    #pragma unroll
    for (int j = 0; j < 32; j += 4)
        *(float4*)(out + j) = *(const float4*)(feats + (size_t)p*32 + j);

    for (int j0 = 0; j0 < 64; j0 += 4) {            // j0 dynamic, k static-unrolled
        float a0 = b2[j0+0], a1 = b2[j0+1], a2 = b2[j0+2], a3 = b2[j0+3];
        #pragma unroll
        for (int k = 0; k < 64; ++k) {
            float s = s1[k];
            const float* wr = &w2[k*64 + j0];
            a0 = fmaf(s, wr[0], a0);
            a1 = fmaf(s, wr[1], a1);
            a2 = fmaf(s, wr[2], a2);
            a3 = fmaf(s, wr[3], a3);
        }
        *(float4*)(out + 32 + j0) =
            make_float4(fmaxf(a0,0.f), fmaxf(a1,0.f), fmaxf(a2,0.f), fmaxf(a3,0.f));
    }
}

// ---------------------------------------------------------------------------
// fp32 GEMM: C[M,N] = act(A[M,K] @ W[K,N] + bias), 128x128x16 tile, 8x8/thread
// ---------------------------------------------------------------------------
#define BM 128
#define BN 128
#define BK 16

__global__ __launch_bounds__(256) void k_gemm(
    const float* __restrict__ A, const float* __restrict__ W,
    const float* __restrict__ bias, float* __restrict__ C,
    int M, int K, int Nn, int relu)
{
    __shared__ float As[BK][BM + 4];
    __shared__ float Bs[BK][BN];
    const int tid = threadIdx.x;
    const int bm = blockIdx.y, bn = blockIdx.x;
    const int tr = tid >> 4, tc = tid & 15;          // 16x16 thread grid, 8x8 each
    const int ar0 = tid >> 2, ac0 = (tid & 3) * 4;   // A-stage mapping
    const int bk0 = tid >> 5, bn0 = (tid & 31) * 4;  // B-stage mapping
    const float* Ab = A + (size_t)bm * BM * K;
    const float* Wb = W + (size_t)bn * BN;

    float acc[8][8];
    #pragma unroll
    for (int i = 0; i < 8; ++i)
        #pragma unroll
        for (int j = 0; j < 8; ++j) acc[i][j] = 0.f;

    for (int k0 = 0; k0 < K; k0 += BK) {
        float4 a0 = *(const float4*)(Ab + (size_t)ar0*K      + k0 + ac0);
        float4 a1 = *(const float4*)(Ab + (size_t)(ar0+64)*K + k0 + ac0);
        float4 w0 = *(const float4*)(Wb + (size_t)(k0+bk0  )*Nn + bn0);
        float4 w1 = *(const float4*)(Wb + (size_t)(k0+bk0+8)*Nn + bn0);
        As[ac0+0][ar0]    = a0.x; As[ac0+1][ar0]    = a0.y;
        As[ac0+2][ar0]    = a0.z; As[ac0+3][ar0]    = a0.w;
        As[ac0+0][ar0+64] = a1.x; As[ac0+1][ar0+64] = a1.y;
        As[ac0+2][ar0+64] = a1.z; As[ac0+3][ar0+64] = a1.w;
        *(float4*)&Bs[bk0  ][bn0] = w0;
        *(float4*)&Bs[bk0+8][bn0] = w1;
        __syncthreads();
        #pragma unroll
        for (int kk = 0; kk < BK; ++kk) {
            float4 av0 = *(const float4*)&As[kk][tr*8];
            float4 av1 = *(const float4*)&As[kk][tr*8+4];
            float4 bv0 = *(const float4*)&Bs[kk][tc*8];
            float4 bv1 = *(const float4*)&Bs[kk][tc*8+4];
            float a[8] = {av0.x,av0.y,av0.z,av0.w, av1.x,av1.y,av1.z,av1.w};
            float b[8] = {bv0.x,bv0.y,bv0.z,bv0.w, bv1.x,bv1.y,bv1.z,bv1.w};
            #pragma unroll
            for (int i = 0; i < 8; ++i)
                #pragma unroll
                for (int j = 0; j < 8; ++j)
                    acc[i][j] = fmaf(a[i], b[j], acc[i][j]);
        }
        __syncthreads();
    }

    float bl[8];
    #pragma unroll
    for (int j = 0; j < 8; ++j) bl[j] = bias[(size_t)bn*BN + tc*8 + j];
    #pragma unroll
    for (int i = 0; i < 8; ++i) {
        int row = bm*BM + tr*8 + i;
        float v[8];
        #pragma unroll
        for (int j = 0; j < 8; ++j) {
            float x = acc[i][j] + bl[j];
            v[j] = relu ? fmaxf(x, 0.f) : x;
        }
        float4* cp = (float4*)(C + (size_t)row*Nn + bn*BN + tc*8);
        cp[0] = make_float4(v[0],v[1],v[2],v[3]);
        cp[1] = make_float4(v[4],v[5],v[6],v[7]);
    }
}

// ---------------------------------------------------------------------------
// score = T4[row,:384] . hw2 + hb2    (one wave per row)
// ---------------------------------------------------------------------------
__global__ __launch_bounds__(256) void k_score(
    const float* __restrict__ T4, const float* __restrict__ hw2,
    const float* __restrict__ hb2, float* __restrict__ scores, int M)
{
    int w = (blockIdx.x * 256 + threadIdx.x) >> 6;
    int lane = threadIdx.x & 63;
    if (w >= M) return;
    const float* row = T4 + (size_t)w * 384;
    float s = 0.f;
    #pragma unroll
    for (int j = 0; j < 384; j += 64) s = fmaf(row[j + lane], hw2[j + lane], s);
    for (int o = 32; o > 0; o >>= 1) s += __shfl_down(s, o, 64);
    if (lane == 0) scores[w] = s + hb2[0];
}

__global__ __launch_bounds__(256) void k_hist(const int* __restrict__ bids,
                                              int* __restrict__ counts)
{
    int i = blockIdx.x * 256 + threadIdx.x;
    if (i < NPTS) atomicAdd(&counts[bids[i]], 1);
}

// ---------------------------------------------------------------------------
// Per-batch top-128 (value desc, index asc tie-break == lax.top_k).
// Writes sel_idx (global point idx or -1), centroids, mask.
// ---------------------------------------------------------------------------
__global__ __launch_bounds__(256) void k_select(
    const float* __restrict__ scores, const int* __restrict__ counts,
    const float* __restrict__ coords, const float* __restrict__ times,
    int* __restrict__ sel_idx, float* __restrict__ out_cent,
    float* __restrict__ out_mask)
{
    __shared__ float val[MAXPB];
    __shared__ float rbv[256];
    __shared__ int   rbi[256];
    __shared__ int   s_off, s_cnt;
    const float NEGINF = -__builtin_inff();
    int b = blockIdx.x, t = threadIdx.x;
    if (t == 0) {
        int off = 0;
        for (int i = 0; i < b; ++i) off += counts[i];
        s_off = off;
        s_cnt = min(counts[b], MAXPB);
    }
    __syncthreads();
    int off = s_off, cnt = s_cnt;
    for (int i = t; i < cnt; i += 256) val[i] = scores[off + i];
    __syncthreads();

    for (int k = 0; k < MT; ++k) {
        int pos;
        if (k < cnt) {
            float bv = NEGINF; int bi = -1;
            for (int i = t; i < cnt; i += 256) {         // ascending -> lowest idx kept
                float v = val[i];
                if (v > bv) { bv = v; bi = i; }
            }
            rbv[t] = bv; rbi[t] = bi;
            __syncthreads();
            for (int s = 128; s > 0; s >>= 1) {
                if (t < s) {
                    float v2 = rbv[t+s]; int i2 = rbi[t+s];
                    if (v2 > rbv[t] ||
                        (v2 == rbv[t] && i2 >= 0 && (rbi[t] < 0 || i2 < rbi[t]))) {
                        rbv[t] = v2; rbi[t] = i2;
                    }
                }
                __syncthreads();
            }
            pos = rbi[0];
            if (t == 0) val[pos] = NEGINF;               // mark taken
        } else {
            pos = k;                                     // NEG_INF padding, idx asc
        }
        __syncthreads();
        if (t == 0) {
            int g = (k < cnt) ? (off + pos) : -1;
            sel_idx[b*MT + k] = g;
            out_mask[b*MT + k] = (k < cnt) ? 1.0f : 0.0f;
            float4 c = make_float4(0.f,0.f,0.f,0.f);
            if (g >= 0)
                c = make_float4(coords[(size_t)g*3+0], coords[(size_t)g*3+1],
                                coords[(size_t)g*3+2], times[g]);
            *(float4*)&out_cent[(size_t)(b*MT + k) * 4] = c;
        }
        __syncthreads();
    }
}

__global__ __launch_bounds__(256) void k_tokens(const float* __restrict__ PF,
                                                const int* __restrict__ sel,
                                                float* __restrict__ out)
{
    int i = blockIdx.x * 256 + threadIdx.x;   // over 8192*192 float4
    int row = i / 192, c = i % 192;
    float4 v = make_float4(0.f,0.f,0.f,0.f);
    if (sel[row] >= 0) v = ((const float4*)PF)[(size_t)row*192 + c];
    ((float4*)out)[(size_t)row*192 + c] = v;
}

// ---------------------------------------------------------------------------
extern "C" void kernel_launch(void* const* d_in, const int* in_sizes, int n_in,
                              void* d_out, int out_size, void* d_ws, size_t ws_size,
                              hipStream_t stream)
{
    const float* coords = (const float*)d_in[0];
    const float* feats  = (const float*)d_in[1];
    const float* times  = (const float*)d_in[2];
    const int*   bids   = (const int*)  d_in[3];
    const float* ln_g = (const float*)d_in[4];
    const float* ln_b = (const float*)d_in[5];
    const float* sw1  = (const float*)d_in[6];
    const float* sb1  = (const float*)d_in[7];
    const float* sw2  = (const float*)d_in[8];
    const float* sb2  = (const float*)d_in[9];
    const float* mw1  = (const float*)d_in[10];
    const float* mb1  = (const float*)d_in[11];
    const float* mw2  = (const float*)d_in[12];
    const float* mb2  = (const float*)d_in[13];
    const float* mw3  = (const float*)d_in[14];
    const float* mb3  = (const float*)d_in[15];
    const float* mw4  = (const float*)d_in[16];
    const float* mb4  = (const float*)d_in[17];
    const float* hw1  = (const float*)d_in[18];
    const float* hb1  = (const float*)d_in[19];
    const float* hw2  = (const float*)d_in[20];
    const float* hb2  = (const float*)d_in[21];

    float* out_tok  = (float*)d_out;                       // 64*128*768
    float* out_cent = out_tok + (size_t)NB*MT*TD;          // 64*128*4
    float* out_mask = out_cent + (size_t)NB*MT*4;          // 64*128

    char* wsb = (char*)d_ws;
    size_t off = 0;
    auto alloc = [&](size_t bytes) {
        char* p = wsb + off;
        off = (off + bytes + 255) & ~(size_t)255;
        return p;
    };
    int*   counts  = (int*)  alloc(NB * 4);
    int*   sel_idx = (int*)  alloc((size_t)NB * MT * 4);
    float* scores  = (float*)alloc((size_t)NPTS * 4);
    size_t base = off;

    int Nc = 8192;                                          // min (final pass needs 8192)
    const int cands[3] = {32768, 16384, 8192};
    for (int ci = 0; ci < 3; ++ci) {
        size_t need = base + (size_t)cands[ci] * (96+256+512+768+768) * 4 + 5*256;
        if (need <= ws_size) { Nc = cands[ci]; break; }
    }
    float* X96 = (float*)alloc((size_t)Nc * 96  * 4);
    float* H1  = (float*)alloc((size_t)Nc * 256 * 4);
    float* H2  = (float*)alloc((size_t)Nc * 512 * 4);
    float* H3  = (float*)alloc((size_t)Nc * 768 * 4);
    float* PF  = (float*)alloc((size_t)Nc * 768 * 4);
    float* T4  = H2;                                        // reuse (H2 dead by then)

    hipMemsetAsync(counts, 0, NB * 4, stream);
    k_hist<<<NPTS/256, 256, 0, stream>>>(bids, counts);

    for (int p0 = 0; p0 < NPTS; p0 += Nc) {
        k_x96<<<Nc/256, 256, 0, stream>>>(coords, feats, times, ln_g, ln_b,
                                          sw1, sb1, sw2, sb2, nullptr, p0, Nc, X96);
        k_gemm<<<dim3(2, Nc/128), 256, 0, stream>>>(X96, mw1, mb1, H1, Nc,  96, 256, 1);
        k_gemm<<<dim3(4, Nc/128), 256, 0, stream>>>(H1,  mw2, mb2, H2, Nc, 256, 512, 1);
        k_gemm<<<dim3(6, Nc/128), 256, 0, stream>>>(H2,  mw3, mb3, H3, Nc, 512, 768, 1);
        k_gemm<<<dim3(6, Nc/128), 256, 0, stream>>>(H3,  mw4, mb4, PF, Nc, 768, 768, 0);
        k_gemm<<<dim3(3, Nc/128), 256, 0, stream>>>(PF,  hw1, hb1, T4, Nc, 768, 384, 1);
        k_score<<<Nc/4, 256, 0, stream>>>(T4, hw2, hb2, scores + p0, Nc);
    }

    k_select<<<NB, 256, 0, stream>>>(scores, counts, coords, times,
                                     sel_idx, out_cent, out_mask);

    // Recompute point_feats for the 8192 selected rows only.
    const int MS = NB * MT;   // 8192
    k_x96<<<MS/256, 256, 0, stream>>>(coords, feats, times, ln_g, ln_b,
                                      sw1, sb1, sw2, sb2, sel_idx, 0, MS, X96);
    k_gemm<<<dim3(2, MS/128), 256, 0, stream>>>(X96, mw1, mb1, H1, MS,  96, 256, 1);
    k_gemm<<<dim3(4, MS/128), 256, 0, stream>>>(H1,  mw2, mb2, H2, MS, 256, 512, 1);
    k_gemm<<<dim3(6, MS/128), 256, 0, stream>>>(H2,  mw3, mb3, H3, MS, 512, 768, 1);
    k_gemm<<<dim3(6, MS/128), 256, 0, stream>>>(H3,  mw4, mb4, PF, MS, 768, 768, 0);
    k_tokens<<<(MS*192)/256, 256, 0, stream>>>(PF, sel_idx, out_tok);
}

// Round 3
// 2741.654 us; speedup vs baseline: 2.2733x; 2.2733x over previous
//
#include <hip/hip_runtime.h>
#include <cstdint>

#define NPTS 131072
#define NB 64
#define MAXPB 2560
#define MT 128
#define TD 768
#define CAND 160
#define MC (NB * CAND)   // 10240 candidate rows

typedef _Float16 f16;
typedef _Float16 f16x8 __attribute__((ext_vector_type(8)));
typedef float f32x4 __attribute__((ext_vector_type(4)));

// split fp32 -> (hi,lo) f16 pair packed in u32: low16 = hi, high16 = lo
__device__ __forceinline__ uint32_t packsplit(float x) {
    f16 h = (f16)x;
    f16 l = (f16)(x - (float)h);
    return ((uint32_t)__builtin_bit_cast(unsigned short, l) << 16) |
           (uint32_t)__builtin_bit_cast(unsigned short, h);
}

// ---------------------------------------------------------------------------
// offsets via binary search on sorted batch_ids
// ---------------------------------------------------------------------------
__global__ void k_counts(const int* __restrict__ bids, int* __restrict__ offs)
{
    int b = threadIdx.x;
    if (b > NB) return;
    int lo = 0, hi = NPTS;
    while (lo < hi) { int mid = (lo + hi) >> 1; if (bids[mid] < b) lo = mid + 1; else hi = mid; }
    offs[b] = lo;
}

// ---------------------------------------------------------------------------
// weight split: W[K][N] fp32 -> Wt_pk[N][K] u32 (hi,lo f16)
// ---------------------------------------------------------------------------
__global__ __launch_bounds__(256) void k_splitw(const float* __restrict__ W,
                                                uint32_t* __restrict__ out,
                                                int K, int N)
{
    int i = blockIdx.x * 256 + threadIdx.x;
    if (i >= K * N) return;
    int n = i / K, k = i % K;
    out[i] = packsplit(W[(size_t)k * N + n]);
}

// ---------------------------------------------------------------------------
// Per-point front-end, PACKED output (scoring pass, contiguous rows)
// ---------------------------------------------------------------------------
__global__ __launch_bounds__(256) void k_x96pk(
    const float* __restrict__ coords, const float* __restrict__ feats,
    const float* __restrict__ times,
    const float* __restrict__ ln_g, const float* __restrict__ ln_b,
    const float* __restrict__ sw1, const float* __restrict__ sb1,
    const float* __restrict__ sw2, const float* __restrict__ sb2,
    int p0, int M, uint32_t* __restrict__ X96pk)
{
    __shared__ float w1[256], w2[4096], b1[64], b2[64];
    int t = threadIdx.x;
    w1[t] = sw1[t];
    for (int i = t; i < 4096; i += 256) w2[i] = sw2[i];
    if (t < 64) { b1[t] = sb1[t]; b2[t] = sb2[t]; }
    __syncthreads();

    int r = blockIdx.x * 256 + t;
    if (r >= M) return;
    int p = p0 + r;
    uint32_t* out = X96pk + (size_t)r * 96;
    float x0 = coords[(size_t)p*3+0], x1 = coords[(size_t)p*3+1];
    float x2 = coords[(size_t)p*3+2], x3 = times[p];
    float mu = 0.25f*(x0+x1+x2+x3);
    float d0 = x0-mu, d1 = x1-mu, d2 = x2-mu, d3 = x3-mu;
    float var = 0.25f*(d0*d0+d1*d1+d2*d2+d3*d3);
    float inv = 1.0f / sqrtf(var + 1e-5f);
    float xn0 = d0*inv*ln_g[0]+ln_b[0];
    float xn1 = d1*inv*ln_g[1]+ln_b[1];
    float xn2 = d2*inv*ln_g[2]+ln_b[2];
    float xn3 = d3*inv*ln_g[3]+ln_b[3];

    float s1[64];
    #pragma unroll
    for (int j = 0; j < 64; ++j) {
        float a = b1[j];
        a = fmaf(xn0, w1[j],       a);
        a = fmaf(xn1, w1[64 + j],  a);
        a = fmaf(xn2, w1[128 + j], a);
        a = fmaf(xn3, w1[192 + j], a);
        s1[j] = fmaxf(a, 0.f);
    }
    #pragma unroll
    for (int j = 0; j < 32; j += 4) {
        float4 f = *(const float4*)(feats + (size_t)p*32 + j);
        *(uint4*)(out + j) = make_uint4(packsplit(f.x), packsplit(f.y),
                                        packsplit(f.z), packsplit(f.w));
    }
    for (int j0 = 0; j0 < 64; j0 += 4) {
        float a0 = b2[j0+0], a1 = b2[j0+1], a2 = b2[j0+2], a3 = b2[j0+3];
        #pragma unroll
        for (int k = 0; k < 64; ++k) {
            float s = s1[k];
            const float* wr = &w2[k*64 + j0];
            a0 = fmaf(s, wr[0], a0);
            a1 = fmaf(s, wr[1], a1);
            a2 = fmaf(s, wr[2], a2);
            a3 = fmaf(s, wr[3], a3);
        }
        *(uint4*)(out + 32 + j0) = make_uint4(
            packsplit(fmaxf(a0,0.f)), packsplit(fmaxf(a1,0.f)),
            packsplit(fmaxf(a2,0.f)), packsplit(fmaxf(a3,0.f)));
    }
}

// ---------------------------------------------------------------------------
// Per-point front-end, FP32 output, gather variant (rescore pass) — round-1
// ---------------------------------------------------------------------------
__global__ __launch_bounds__(256) void k_x96f(
    const float* __restrict__ coords, const float* __restrict__ feats,
    const float* __restrict__ times,
    const float* __restrict__ ln_g, const float* __restrict__ ln_b,
    const float* __restrict__ sw1, const float* __restrict__ sb1,
    const float* __restrict__ sw2, const float* __restrict__ sb2,
    const int* __restrict__ sel, int M, float* __restrict__ X96)
{
    __shared__ float w1[256], w2[4096], b1[64], b2[64];
    int t = threadIdx.x;
    w1[t] = sw1[t];
    for (int i = t; i < 4096; i += 256) w2[i] = sw2[i];
    if (t < 64) { b1[t] = sb1[t]; b2[t] = sb2[t]; }
    __syncthreads();

    int r = blockIdx.x * 256 + t;
    if (r >= M) return;
    int p = sel[r];
    float* out = X96 + (size_t)r * 96;
    if (p < 0) {
        for (int j = 0; j < 96; j += 4) *(float4*)(out + j) = make_float4(0.f,0.f,0.f,0.f);
        return;
    }
    float x0 = coords[(size_t)p*3+0], x1 = coords[(size_t)p*3+1];
    float x2 = coords[(size_t)p*3+2], x3 = times[p];
    float mu = 0.25f*(x0+x1+x2+x3);
    float d0 = x0-mu, d1 = x1-mu, d2 = x2-mu, d3 = x3-mu;
    float var = 0.25f*(d0*d0+d1*d1+d2*d2+d3*d3);
    float inv = 1.0f / sqrtf(var + 1e-5f);
    float xn0 = d0*inv*ln_g[0]+ln_b[0];
    float xn1 = d1*inv*ln_g[1]+ln_b[1];
    float xn2 = d2*inv*ln_g[2]+ln_b[2];
    float xn3 = d3*inv*ln_g[3]+ln_b[3];

    float s1[64];
    #pragma unroll
    for (int j = 0; j < 64; ++j) {
        float a = b1[j];
        a = fmaf(xn0, w1[j],       a);
        a = fmaf(xn1, w1[64 + j],  a);
        a = fmaf(xn2, w1[128 + j], a);
        a = fmaf(xn3, w1[192 + j], a);
        s1[j] = fmaxf(a, 0.f);
    }
    #pragma unroll
    for (int j = 0; j < 32; j += 4)
        *(float4*)(out + j) = *(const float4*)(feats + (size_t)p*32 + j);

    for (int j0 = 0; j0 < 64; j0 += 4) {
        float a0 = b2[j0+0], a1 = b2[j0+1], a2 = b2[j0+2], a3 = b2[j0+3];
        #pragma unroll
        for (int k = 0; k < 64; ++k) {
            float s = s1[k];
            const float* wr = &w2[k*64 + j0];
            a0 = fmaf(s, wr[0], a0);
            a1 = fmaf(s, wr[1], a1);
            a2 = fmaf(s, wr[2], a2);
            a3 = fmaf(s, wr[3], a3);
        }
        *(float4*)(out + 32 + j0) =
            make_float4(fmaxf(a0,0.f), fmaxf(a1,0.f), fmaxf(a2,0.f), fmaxf(a3,0.f));
    }
}

// ---------------------------------------------------------------------------
// fp16x2-split MFMA GEMM (scoring pass): C = act(A @ Wt^T + bias)
// ---------------------------------------------------------------------------
__global__ __launch_bounds__(256, 2) void k_mgemm(
    const uint32_t* __restrict__ Apk, const uint32_t* __restrict__ Bpk,
    const float* __restrict__ bias, uint32_t* __restrict__ Opk,
    float* __restrict__ Of, int M, int K, int N, int relu)
{
    __shared__ ushort sAh[4096], sAl[4096], sBh[4096], sBl[4096];
    const int tid = threadIdx.x;
    const int bm = blockIdx.y, bn = blockIdx.x;
    const int lane = tid & 63, w = tid >> 6;
    const int wm = w >> 1, wn = w & 1;
    const int lr = lane & 15, lg = lane >> 4;

    const int sr = tid >> 1;
    const int k0 = (tid & 1) << 4;
    const uint32_t* ag = Apk + (size_t)(bm*128 + sr) * K + k0;
    const uint32_t* bg = Bpk + (size_t)(bn*128 + sr) * K + k0;
    const int swz = ((sr >> 1) & 3) << 3;
    const int sbase = sr * 32;

    int aoff[4], boff[4];
    #pragma unroll
    for (int m = 0; m < 4; ++m) {
        int row = wm*64 + m*16 + lr;
        aoff[m] = row*32 + ((lg*8) ^ (((row>>1)&3)<<3));
    }
    #pragma unroll
    for (int n = 0; n < 4; ++n) {
        int row = wn*64 + n*16 + lr;
        boff[n] = row*32 + ((lg*8) ^ (((row>>1)&3)<<3));
    }

    f32x4 acc[4][4];
    #pragma unroll
    for (int m = 0; m < 4; ++m)
        #pragma unroll
        for (int n = 0; n < 4; ++n) acc[m][n] = (f32x4){0.f,0.f,0.f,0.f};

    for (int kt = 0; kt < K; kt += 32) {
        __syncthreads();
        #pragma unroll
        for (int j = 0; j < 4; ++j) {
            uint4 q = *(const uint4*)(ag + kt + 4*j);
            uint32_t h0 = __builtin_amdgcn_perm(q.y, q.x, 0x05040100u);
            uint32_t h1 = __builtin_amdgcn_perm(q.w, q.z, 0x05040100u);
            uint32_t l0 = __builtin_amdgcn_perm(q.y, q.x, 0x07060302u);
            uint32_t l1 = __builtin_amdgcn_perm(q.w, q.z, 0x07060302u);
            int kx = sbase + ((k0 + 4*j) ^ swz);
            *(uint2*)&sAh[kx] = make_uint2(h0, h1);
            *(uint2*)&sAl[kx] = make_uint2(l0, l1);
        }
        #pragma unroll
        for (int j = 0; j < 4; ++j) {
            uint4 q = *(const uint4*)(bg + kt + 4*j);
            uint32_t h0 = __builtin_amdgcn_perm(q.y, q.x, 0x05040100u);
            uint32_t h1 = __builtin_amdgcn_perm(q.w, q.z, 0x05040100u);
            uint32_t l0 = __builtin_amdgcn_perm(q.y, q.x, 0x07060302u);
            uint32_t l1 = __builtin_amdgcn_perm(q.w, q.z, 0x07060302u);
            int kx = sbase + ((k0 + 4*j) ^ swz);
            *(uint2*)&sBh[kx] = make_uint2(h0, h1);
            *(uint2*)&sBl[kx] = make_uint2(l0, l1);
        }
        __syncthreads();

        f16x8 ah[4], al[4], bh[4], bl[4];
        #pragma unroll
        for (int m = 0; m < 4; ++m) {
            ah[m] = *(const f16x8*)&sAh[aoff[m]];
            al[m] = *(const f16x8*)&sAl[aoff[m]];
        }
        #pragma unroll
        for (int n = 0; n < 4; ++n) {
            bh[n] = *(const f16x8*)&sBh[boff[n]];
            bl[n] = *(const f16x8*)&sBl[boff[n]];
        }
        #pragma unroll
        for (int m = 0; m < 4; ++m)
            #pragma unroll
            for (int n = 0; n < 4; ++n) {
                acc[m][n] = __builtin_amdgcn_mfma_f32_16x16x32_f16(al[m], bh[n], acc[m][n], 0, 0, 0);
                acc[m][n] = __builtin_amdgcn_mfma_f32_16x16x32_f16(ah[m], bl[n], acc[m][n], 0, 0, 0);
                acc[m][n] = __builtin_amdgcn_mfma_f32_16x16x32_f16(ah[m], bh[n], acc[m][n], 0, 0, 0);
            }
    }

    #pragma unroll
    for (int n = 0; n < 4; ++n) {
        int col = bn*128 + wn*64 + n*16 + lr;
        float bb = bias[col];
        #pragma unroll
        for (int m = 0; m < 4; ++m) {
            int row0 = bm*128 + wm*64 + m*16 + lg*4;
            #pragma unroll
            for (int q = 0; q < 4; ++q) {
                float v = acc[m][n][q] + bb;
                if (relu) v = fmaxf(v, 0.f);
                size_t idx = (size_t)(row0 + q) * N + col;
                if (Opk) Opk[idx] = packsplit(v);
                if (Of)  Of[idx]  = v;
            }
        }
    }
}

// ---------------------------------------------------------------------------
// fp32 GEMM (rescore pass) — round-1 validated
// ---------------------------------------------------------------------------
#define BM 128
#define BN 128
#define BK 16

__global__ __launch_bounds__(256) void k_gemm(
    const float* __restrict__ A, const float* __restrict__ W,
    const float* __restrict__ bias, float* __restrict__ C,
    int M, int K, int Nn, int relu)
{
    __shared__ float As[BK][BM + 4];
    __shared__ float Bs[BK][BN];
    const int tid = threadIdx.x;
    const int bm = blockIdx.y, bn = blockIdx.x;
    const int tr = tid >> 4, tc = tid & 15;
    const int ar0 = tid >> 2, ac0 = (tid & 3) * 4;
    const int bk0 = tid >> 5, bn0 = (tid & 31) * 4;
    const float* Ab = A + (size_t)bm * BM * K;
    const float* Wb = W + (size_t)bn * BN;

    float acc[8][8];
    #pragma unroll
    for (int i = 0; i < 8; ++i)
        #pragma unroll
        for (int j = 0; j < 8; ++j) acc[i][j] = 0.f;

    for (int k0 = 0; k0 < K; k0 += BK) {
        float4 a0 = *(const float4*)(Ab + (size_t)ar0*K      + k0 + ac0);
        float4 a1 = *(const float4*)(Ab + (size_t)(ar0+64)*K + k0 + ac0);
        float4 w0 = *(const float4*)(Wb + (size_t)(k0+bk0  )*Nn + bn0);
        float4 w1 = *(const float4*)(Wb + (size_t)(k0+bk0+8)*Nn + bn0);
        As[ac0+0][ar0]    = a0.x; As[ac0+1][ar0]    = a0.y;
        As[ac0+2][ar0]    = a0.z; As[ac0+3][ar0]    = a0.w;
        As[ac0+0][ar0+64] = a1.x; As[ac0+1][ar0+64] = a1.y;
        As[ac0+2][ar0+64] = a1.z; As[ac0+3][ar0+64] = a1.w;
        *(float4*)&Bs[bk0  ][bn0] = w0;
        *(float4*)&Bs[bk0+8][bn0] = w1;
        __syncthreads();
        #pragma unroll
        for (int kk = 0; kk < BK; ++kk) {
            float4 av0 = *(const float4*)&As[kk][tr*8];
            float4 av1 = *(const float4*)&As[kk][tr*8+4];
            float4 bv0 = *(const float4*)&Bs[kk][tc*8];
            float4 bv1 = *(const float4*)&Bs[kk][tc*8+4];
            float a[8] = {av0.x,av0.y,av0.z,av0.w, av1.x,av1.y,av1.z,av1.w};
            float b[8] = {bv0.x,bv0.y,bv0.z,bv0.w, bv1.x,bv1.y,bv1.z,bv1.w};
            #pragma unroll
            for (int i = 0; i < 8; ++i)
                #pragma unroll
                for (int j = 0; j < 8; ++j)
                    acc[i][j] = fmaf(a[i], b[j], acc[i][j]);
        }
        __syncthreads();
    }

    float bl[8];
    #pragma unroll
    for (int j = 0; j < 8; ++j) bl[j] = bias[(size_t)bn*BN + tc*8 + j];
    #pragma unroll
    for (int i = 0; i < 8; ++i) {
        int row = bm*BM + tr*8 + i;
        float v[8];
        #pragma unroll
        for (int j = 0; j < 8; ++j) {
            float x = acc[i][j] + bl[j];
            v[j] = relu ? fmaxf(x, 0.f) : x;
        }
        float4* cp = (float4*)(C + (size_t)row*Nn + bn*BN + tc*8);
        cp[0] = make_float4(v[0],v[1],v[2],v[3]);
        cp[1] = make_float4(v[4],v[5],v[6],v[7]);
    }
}

// ---------------------------------------------------------------------------
// score = T4[row,:384] . hw2 + hb2
// ---------------------------------------------------------------------------
__global__ __launch_bounds__(256) void k_score(
    const float* __restrict__ T4, const float* __restrict__ hw2,
    const float* __restrict__ hb2, float* __restrict__ scores, int M)
{
    int w = (blockIdx.x * 256 + threadIdx.x) >> 6;
    int lane = threadIdx.x & 63;
    if (w >= M) return;
    const float* row = T4 + (size_t)w * 384;
    float s = 0.f;
    #pragma unroll
    for (int j = 0; j < 384; j += 64) s = fmaf(row[j + lane], hw2[j + lane], s);
    for (int o = 32; o > 0; o >>= 1) s += __shfl_down(s, o, 64);
    if (lane == 0) scores[w] = s + hb2[0];
}

// ---------------------------------------------------------------------------
// Stage 1: per-batch top-CAND by split scores (value desc, pos asc)
// ---------------------------------------------------------------------------
__global__ __launch_bounds__(256) void k_topcand(
    const float* __restrict__ scores, const int* __restrict__ offs,
    int* __restrict__ cand_g, int* __restrict__ cand_p)
{
    __shared__ float val[MAXPB];
    __shared__ float rbv[256];
    __shared__ int   rbi[256];
    const float NEGINF = -__builtin_inff();
    int b = blockIdx.x, t = threadIdx.x;
    int off = offs[b];
    int cnt = min(offs[b+1] - off, MAXPB);
    for (int i = t; i < cnt; i += 256) val[i] = scores[off + i];
    __syncthreads();

    for (int k = 0; k < CAND; ++k) {
        if (k < cnt) {
            float bv = NEGINF; int bi = -1;
            for (int i = t; i < cnt; i += 256) {
                float v = val[i];
                if (v > bv) { bv = v; bi = i; }
            }
            rbv[t] = bv; rbi[t] = bi;
            __syncthreads();
            for (int s = 128; s > 0; s >>= 1) {
                if (t < s) {
                    float v2 = rbv[t+s]; int i2 = rbi[t+s];
                    if (v2 > rbv[t] ||
                        (v2 == rbv[t] && i2 >= 0 && (rbi[t] < 0 || i2 < rbi[t]))) {
                        rbv[t] = v2; rbi[t] = i2;
                    }
                }
                __syncthreads();
            }
            int pos = rbi[0];
            if (t == 0) {
                val[pos] = NEGINF;
                cand_g[b*CAND + k] = off + pos;
                cand_p[b*CAND + k] = pos;
            }
        } else if (t == 0) {
            cand_g[b*CAND + k] = -1;
            cand_p[b*CAND + k] = MAXPB + k;
        }
        __syncthreads();
    }
}

// ---------------------------------------------------------------------------
// Stage 2: per-batch top-MT among CAND candidates by fp32 score
// (value desc, per-batch pos asc). Emits tok_src, centroids, mask.
// ---------------------------------------------------------------------------
__global__ __launch_bounds__(256) void k_fsel(
    const float* __restrict__ fscores, const int* __restrict__ offs,
    const int* __restrict__ cand_g, const int* __restrict__ cand_p,
    const float* __restrict__ coords, const float* __restrict__ times,
    int* __restrict__ tok_src, float* __restrict__ out_cent,
    float* __restrict__ out_mask)
{
    __shared__ float fv[CAND];
    __shared__ int   fp_[CAND];
    __shared__ float rbv[256];
    __shared__ int   rbp[256], rbj[256];
    const float NEGINF = -__builtin_inff();
    int b = blockIdx.x, t = threadIdx.x;
    int cnt = min(offs[b+1] - offs[b], MAXPB);
    int cntc = min(cnt, CAND);
    if (t < CAND) {
        fv[t]  = (t < cntc) ? fscores[b*CAND + t] : NEGINF;
        fp_[t] = cand_p[b*CAND + t];
    }
    __syncthreads();

    for (int k = 0; k < MT; ++k) {
        if (k < cntc) {
            float bv = NEGINF; int bp = 0x7fffffff, bj = -1;
            if (t < cntc) {
                float v = fv[t];
                if (v > NEGINF) { bv = v; bp = fp_[t]; bj = t; }
            }
            rbv[t] = bv; rbp[t] = bp; rbj[t] = bj;
            __syncthreads();
            for (int s = 128; s > 0; s >>= 1) {
                if (t < s) {
                    float v2 = rbv[t+s]; int p2 = rbp[t+s], j2 = rbj[t+s];
                    if (j2 >= 0 && (rbj[t] < 0 || v2 > rbv[t] ||
                                    (v2 == rbv[t] && p2 < rbp[t]))) {
                        rbv[t] = v2; rbp[t] = p2; rbj[t] = j2;
                    }
                }
                __syncthreads();
            }
            int jst = rbj[0];
            if (t == 0) {
                fv[jst] = NEGINF;
                int row = b*CAND + jst;
                int g = cand_g[row];
                tok_src[b*MT + k] = row;
                out_mask[b*MT + k] = 1.0f;
                *(float4*)&out_cent[(size_t)(b*MT + k) * 4] =
                    make_float4(coords[(size_t)g*3+0], coords[(size_t)g*3+1],
                                coords[(size_t)g*3+2], times[g]);
            }
        } else if (t == 0) {
            tok_src[b*MT + k] = -1;
            out_mask[b*MT + k] = 0.0f;
            *(float4*)&out_cent[(size_t)(b*MT + k) * 4] = make_float4(0.f,0.f,0.f,0.f);
        }
        __syncthreads();
    }
}

// gather tokens from candidate point_feats
__global__ __launch_bounds__(256) void k_tokens(const float* __restrict__ PFc,
                                                const int* __restrict__ tok_src,
                                                float* __restrict__ out)
{
    int i = blockIdx.x * 256 + threadIdx.x;   // 8192*192 float4
    int row = i / 192, c = i % 192;
    int src = tok_src[row];
    float4 v = make_float4(0.f,0.f,0.f,0.f);
    if (src >= 0) v = ((const float4*)PFc)[(size_t)src*192 + c];
    ((float4*)out)[(size_t)row*192 + c] = v;
}

// ---------------------------------------------------------------------------
extern "C" void kernel_launch(void* const* d_in, const int* in_sizes, int n_in,
                              void* d_out, int out_size, void* d_ws, size_t ws_size,
                              hipStream_t stream)
{
    const float* coords = (const float*)d_in[0];
    const float* feats  = (const float*)d_in[1];
    const float* times  = (const float*)d_in[2];
    const int*   bids   = (const int*)  d_in[3];
    const float* ln_g = (const float*)d_in[4];
    const float* ln_b = (const float*)d_in[5];
    const float* sw1  = (const float*)d_in[6];
    const float* sb1  = (const float*)d_in[7];
    const float* sw2  = (const float*)d_in[8];
    const float* sb2  = (const float*)d_in[9];
    const float* mw1  = (const float*)d_in[10];
    const float* mb1  = (const float*)d_in[11];
    const float* mw2  = (const float*)d_in[12];
    const float* mb2  = (const float*)d_in[13];
    const float* mw3  = (const float*)d_in[14];
    const float* mb3  = (const float*)d_in[15];
    const float* mw4  = (const float*)d_in[16];
    const float* mb4  = (const float*)d_in[17];
    const float* hw1  = (const float*)d_in[18];
    const float* hb1  = (const float*)d_in[19];
    const float* hw2  = (const float*)d_in[20];
    const float* hb2  = (const float*)d_in[21];

    float* out_tok  = (float*)d_out;
    float* out_cent = out_tok + (size_t)NB*MT*TD;
    float* out_mask = out_cent + (size_t)NB*MT*4;

    char* wsb = (char*)d_ws;
    size_t off = 0;
    auto alloc = [&](size_t bytes) {
        char* p = wsb + off;
        off = (off + bytes + 255) & ~(size_t)255;
        return p;
    };
    int*      offs    = (int*)     alloc((NB + 1) * 4);
    float*    scores  = (float*)   alloc((size_t)NPTS * 4);
    float*    fscores = (float*)   alloc((size_t)MC * 4);
    int*      cand_g  = (int*)     alloc((size_t)MC * 4);
    int*      cand_p  = (int*)     alloc((size_t)MC * 4);
    int*      tok_src = (int*)     alloc((size_t)NB * MT * 4);
    uint32_t* wt1pk   = (uint32_t*)alloc((size_t)96  * 256 * 4);
    uint32_t* wt2pk   = (uint32_t*)alloc((size_t)256 * 512 * 4);
    uint32_t* wt3pk   = (uint32_t*)alloc((size_t)512 * 768 * 4);
    uint32_t* wt4pk   = (uint32_t*)alloc((size_t)768 * 768 * 4);
    uint32_t* ht1pk   = (uint32_t*)alloc((size_t)768 * 384 * 4);
    size_t base = off;

    int Nc = MC;                                    // floor: rescore needs MC rows
    const int cands[3] = {32768, 16384, MC};
    for (int ci = 0; ci < 3; ++ci) {
        size_t need = base + (size_t)cands[ci] * (96+256+512+768+768) * 4 + 6*256;
        if (need <= ws_size) { Nc = cands[ci]; break; }
    }
    char* X96b = alloc((size_t)Nc * 96  * 4);
    char* H1b  = alloc((size_t)Nc * 256 * 4);
    char* H2b  = alloc((size_t)Nc * 512 * 4);
    char* H3b  = alloc((size_t)Nc * 768 * 4);
    char* PFb  = alloc((size_t)Nc * 768 * 4);

    // ---------- setup ----------
    k_counts<<<1, 128, 0, stream>>>(bids, offs);
    k_splitw<<<(96*256 +255)/256, 256, 0, stream>>>(mw1, wt1pk,  96, 256);
    k_splitw<<<(256*512+255)/256, 256, 0, stream>>>(mw2, wt2pk, 256, 512);
    k_splitw<<<(512*768+255)/256, 256, 0, stream>>>(mw3, wt3pk, 512, 768);
    k_splitw<<<(768*768+255)/256, 256, 0, stream>>>(mw4, wt4pk, 768, 768);
    k_splitw<<<(768*384+255)/256, 256, 0, stream>>>(hw1, ht1pk, 768, 384);

    // ---------- stage 1: split-MFMA scoring over all points ----------
    {
        uint32_t* X96pk = (uint32_t*)X96b;
        uint32_t* H1pk  = (uint32_t*)H1b;
        uint32_t* H2pk  = (uint32_t*)H2b;
        uint32_t* H3pk  = (uint32_t*)H3b;
        uint32_t* PFpk  = (uint32_t*)PFb;
        float*    T4    = (float*)H2b;     // H2 dead by head time; 384f <= 512u32
        for (int p0 = 0; p0 < NPTS; p0 += Nc) {
            int Mi = min(Nc, NPTS - p0);
            k_x96pk<<<(Mi+255)/256, 256, 0, stream>>>(coords, feats, times, ln_g, ln_b,
                                                      sw1, sb1, sw2, sb2, p0, Mi, X96pk);
            k_mgemm<<<dim3(2, Mi/128), 256, 0, stream>>>(X96pk, wt1pk, mb1, H1pk, nullptr, Mi,  96, 256, 1);
            k_mgemm<<<dim3(4, Mi/128), 256, 0, stream>>>(H1pk,  wt2pk, mb2, H2pk, nullptr, Mi, 256, 512, 1);
            k_mgemm<<<dim3(6, Mi/128), 256, 0, stream>>>(H2pk,  wt3pk, mb3, H3pk, nullptr, Mi, 512, 768, 1);
            k_mgemm<<<dim3(6, Mi/128), 256, 0, stream>>>(H3pk,  wt4pk, mb4, PFpk, nullptr, Mi, 768, 768, 0);
            k_mgemm<<<dim3(3, Mi/128), 256, 0, stream>>>(PFpk,  ht1pk, hb1, nullptr, T4,   Mi, 768, 384, 1);
            k_score<<<(Mi+3)/4, 256, 0, stream>>>(T4, hw2, hb2, scores + p0, Mi);
        }
    }

    // ---------- stage 2: capture top-CAND per batch ----------
    k_topcand<<<NB, 256, 0, stream>>>(scores, offs, cand_g, cand_p);

    // ---------- stage 3: fp32 rescore of candidates (round-1 validated path) --
    {
        float* X96 = (float*)X96b;
        float* H1  = (float*)H1b;
        float* H2  = (float*)H2b;
        float* H3  = (float*)H3b;
        float* PFc = (float*)PFb;
        float* T4  = (float*)H2b;          // H2 dead by head time
        k_x96f<<<MC/256, 256, 0, stream>>>(coords, feats, times, ln_g, ln_b,
                                           sw1, sb1, sw2, sb2, cand_g, MC, X96);
        k_gemm<<<dim3(2, MC/128), 256, 0, stream>>>(X96, mw1, mb1, H1, MC,  96, 256, 1);
        k_gemm<<<dim3(4, MC/128), 256, 0, stream>>>(H1,  mw2, mb2, H2, MC, 256, 512, 1);
        k_gemm<<<dim3(6, MC/128), 256, 0, stream>>>(H2,  mw3, mb3, H3, MC, 512, 768, 1);
        k_gemm<<<dim3(6, MC/128), 256, 0, stream>>>(H3,  mw4, mb4, PFc, MC, 768, 768, 0);
        k_gemm<<<dim3(3, MC/128), 256, 0, stream>>>(PFc, hw1, hb1, T4, MC, 768, 384, 1);
        k_score<<<MC/4, 256, 0, stream>>>(T4, hw2, hb2, fscores, MC);

        // ---------- stage 4: final top-128 per batch on fp32 scores ----------
        k_fsel<<<NB, 256, 0, stream>>>(fscores, offs, cand_g, cand_p,
                                       coords, times, tok_src, out_cent, out_mask);
        k_tokens<<<(NB*MT*192)/256, 256, 0, stream>>>(PFc, tok_src, out_tok);
    }
}

// Round 4
// 2400.580 us; speedup vs baseline: 2.5963x; 1.1421x over previous
//
#include <hip/hip_runtime.h>
#include <cstdint>

#define NPTS 131072
#define NB 64
#define MAXPB 2560
#define MT 128
#define TD 768
#define CAND 160
#define MC (NB * CAND)   // 10240 candidate rows

typedef _Float16 f16;
typedef _Float16 f16x8 __attribute__((ext_vector_type(8)));
typedef float f32x4 __attribute__((ext_vector_type(4)));

// split fp32 -> (hi,lo) f16 pair packed in u32: low16 = hi, high16 = lo
__device__ __forceinline__ uint32_t packsplit(float x) {
    f16 h = (f16)x;
    f16 l = (f16)(x - (float)h);
    return ((uint32_t)__builtin_bit_cast(unsigned short, l) << 16) |
           (uint32_t)__builtin_bit_cast(unsigned short, h);
}

// float -> order-preserving u32 (unsigned asc == float asc)
__device__ __forceinline__ uint32_t sortable(float f) {
    uint32_t u = __builtin_bit_cast(uint32_t, f);
    return u ^ (uint32_t)(((int32_t)u >> 31) | 0x80000000);
}

// ---------------------------------------------------------------------------
// offsets via binary search on sorted batch_ids
// ---------------------------------------------------------------------------
__global__ void k_counts(const int* __restrict__ bids, int* __restrict__ offs)
{
    int b = threadIdx.x;
    if (b > NB) return;
    int lo = 0, hi = NPTS;
    while (lo < hi) { int mid = (lo + hi) >> 1; if (bids[mid] < b) lo = mid + 1; else hi = mid; }
    offs[b] = lo;
}

// ---------------------------------------------------------------------------
// weight split: W[K][N] fp32 -> Wt_pk[N][K] u32 (hi,lo f16)
// ---------------------------------------------------------------------------
__global__ __launch_bounds__(256) void k_splitw(const float* __restrict__ W,
                                                uint32_t* __restrict__ out,
                                                int K, int N)
{
    int i = blockIdx.x * 256 + threadIdx.x;
    if (i >= K * N) return;
    int n = i / K, k = i % K;
    out[i] = packsplit(W[(size_t)k * N + n]);
}

// ---------------------------------------------------------------------------
// Per-point front-end, PACKED output (scoring pass, contiguous rows)
// ---------------------------------------------------------------------------
__global__ __launch_bounds__(256) void k_x96pk(
    const float* __restrict__ coords, const float* __restrict__ feats,
    const float* __restrict__ times,
    const float* __restrict__ ln_g, const float* __restrict__ ln_b,
    const float* __restrict__ sw1, const float* __restrict__ sb1,
    const float* __restrict__ sw2, const float* __restrict__ sb2,
    int p0, int M, uint32_t* __restrict__ X96pk)
{
    __shared__ float w1[256], w2[4096], b1[64], b2[64];
    int t = threadIdx.x;
    w1[t] = sw1[t];
    for (int i = t; i < 4096; i += 256) w2[i] = sw2[i];
    if (t < 64) { b1[t] = sb1[t]; b2[t] = sb2[t]; }
    __syncthreads();

    int r = blockIdx.x * 256 + t;
    if (r >= M) return;
    int p = p0 + r;
    uint32_t* out = X96pk + (size_t)r * 96;
    float x0 = coords[(size_t)p*3+0], x1 = coords[(size_t)p*3+1];
    float x2 = coords[(size_t)p*3+2], x3 = times[p];
    float mu = 0.25f*(x0+x1+x2+x3);
    float d0 = x0-mu, d1 = x1-mu, d2 = x2-mu, d3 = x3-mu;
    float var = 0.25f*(d0*d0+d1*d1+d2*d2+d3*d3);
    float inv = 1.0f / sqrtf(var + 1e-5f);
    float xn0 = d0*inv*ln_g[0]+ln_b[0];
    float xn1 = d1*inv*ln_g[1]+ln_b[1];
    float xn2 = d2*inv*ln_g[2]+ln_b[2];
    float xn3 = d3*inv*ln_g[3]+ln_b[3];

    float s1[64];
    #pragma unroll
    for (int j = 0; j < 64; ++j) {
        float a = b1[j];
        a = fmaf(xn0, w1[j],       a);
        a = fmaf(xn1, w1[64 + j],  a);
        a = fmaf(xn2, w1[128 + j], a);
        a = fmaf(xn3, w1[192 + j], a);
        s1[j] = fmaxf(a, 0.f);
    }
    #pragma unroll
    for (int j = 0; j < 32; j += 4) {
        float4 f = *(const float4*)(feats + (size_t)p*32 + j);
        *(uint4*)(out + j) = make_uint4(packsplit(f.x), packsplit(f.y),
                                        packsplit(f.z), packsplit(f.w));
    }
    for (int j0 = 0; j0 < 64; j0 += 4) {
        float a0 = b2[j0+0], a1 = b2[j0+1], a2 = b2[j0+2], a3 = b2[j0+3];
        #pragma unroll
        for (int k = 0; k < 64; ++k) {
            float s = s1[k];
            const float* wr = &w2[k*64 + j0];
            a0 = fmaf(s, wr[0], a0);
            a1 = fmaf(s, wr[1], a1);
            a2 = fmaf(s, wr[2], a2);
            a3 = fmaf(s, wr[3], a3);
        }
        *(uint4*)(out + 32 + j0) = make_uint4(
            packsplit(fmaxf(a0,0.f)), packsplit(fmaxf(a1,0.f)),
            packsplit(fmaxf(a2,0.f)), packsplit(fmaxf(a3,0.f)));
    }
}

// ---------------------------------------------------------------------------
// Per-point front-end, FP32 output, gather variant (rescore pass)
// ---------------------------------------------------------------------------
__global__ __launch_bounds__(256) void k_x96f(
    const float* __restrict__ coords, const float* __restrict__ feats,
    const float* __restrict__ times,
    const float* __restrict__ ln_g, const float* __restrict__ ln_b,
    const float* __restrict__ sw1, const float* __restrict__ sb1,
    const float* __restrict__ sw2, const float* __restrict__ sb2,
    const int* __restrict__ sel, int M, float* __restrict__ X96)
{
    __shared__ float w1[256], w2[4096], b1[64], b2[64];
    int t = threadIdx.x;
    w1[t] = sw1[t];
    for (int i = t; i < 4096; i += 256) w2[i] = sw2[i];
    if (t < 64) { b1[t] = sb1[t]; b2[t] = sb2[t]; }
    __syncthreads();

    int r = blockIdx.x * 256 + t;
    if (r >= M) return;
    int p = sel[r];
    float* out = X96 + (size_t)r * 96;
    if (p < 0) {
        for (int j = 0; j < 96; j += 4) *(float4*)(out + j) = make_float4(0.f,0.f,0.f,0.f);
        return;
    }
    float x0 = coords[(size_t)p*3+0], x1 = coords[(size_t)p*3+1];
    float x2 = coords[(size_t)p*3+2], x3 = times[p];
    float mu = 0.25f*(x0+x1+x2+x3);
    float d0 = x0-mu, d1 = x1-mu, d2 = x2-mu, d3 = x3-mu;
    float var = 0.25f*(d0*d0+d1*d1+d2*d2+d3*d3);
    float inv = 1.0f / sqrtf(var + 1e-5f);
    float xn0 = d0*inv*ln_g[0]+ln_b[0];
    float xn1 = d1*inv*ln_g[1]+ln_b[1];
    float xn2 = d2*inv*ln_g[2]+ln_b[2];
    float xn3 = d3*inv*ln_g[3]+ln_b[3];

    float s1[64];
    #pragma unroll
    for (int j = 0; j < 64; ++j) {
        float a = b1[j];
        a = fmaf(xn0, w1[j],       a);
        a = fmaf(xn1, w1[64 + j],  a);
        a = fmaf(xn2, w1[128 + j], a);
        a = fmaf(xn3, w1[192 + j], a);
        s1[j] = fmaxf(a, 0.f);
    }
    #pragma unroll
    for (int j = 0; j < 32; j += 4)
        *(float4*)(out + j) = *(const float4*)(feats + (size_t)p*32 + j);

    for (int j0 = 0; j0 < 64; j0 += 4) {
        float a0 = b2[j0+0], a1 = b2[j0+1], a2 = b2[j0+2], a3 = b2[j0+3];
        #pragma unroll
        for (int k = 0; k < 64; ++k) {
            float s = s1[k];
            const float* wr = &w2[k*64 + j0];
            a0 = fmaf(s, wr[0], a0);
            a1 = fmaf(s, wr[1], a1);
            a2 = fmaf(s, wr[2], a2);
            a3 = fmaf(s, wr[3], a3);
        }
        *(float4*)(out + 32 + j0) =
            make_float4(fmaxf(a0,0.f), fmaxf(a1,0.f), fmaxf(a2,0.f), fmaxf(a3,0.f));
    }
}

// ---------------------------------------------------------------------------
// fp16x2-split MFMA GEMM (scoring pass): C = act(A @ Wt^T + bias)
// ---------------------------------------------------------------------------
__global__ __launch_bounds__(256, 2) void k_mgemm(
    const uint32_t* __restrict__ Apk, const uint32_t* __restrict__ Bpk,
    const float* __restrict__ bias, uint32_t* __restrict__ Opk,
    float* __restrict__ Of, int M, int K, int N, int relu)
{
    __shared__ ushort sAh[4096], sAl[4096], sBh[4096], sBl[4096];
    const int tid = threadIdx.x;
    const int bm = blockIdx.y, bn = blockIdx.x;
    const int lane = tid & 63, w = tid >> 6;
    const int wm = w >> 1, wn = w & 1;
    const int lr = lane & 15, lg = lane >> 4;

    const int sr = tid >> 1;
    const int k0 = (tid & 1) << 4;
    const uint32_t* ag = Apk + (size_t)(bm*128 + sr) * K + k0;
    const uint32_t* bg = Bpk + (size_t)(bn*128 + sr) * K + k0;
    const int swz = ((sr >> 1) & 3) << 3;
    const int sbase = sr * 32;

    int aoff[4], boff[4];
    #pragma unroll
    for (int m = 0; m < 4; ++m) {
        int row = wm*64 + m*16 + lr;
        aoff[m] = row*32 + ((lg*8) ^ (((row>>1)&3)<<3));
    }
    #pragma unroll
    for (int n = 0; n < 4; ++n) {
        int row = wn*64 + n*16 + lr;
        boff[n] = row*32 + ((lg*8) ^ (((row>>1)&3)<<3));
    }

    f32x4 acc[4][4];
    #pragma unroll
    for (int m = 0; m < 4; ++m)
        #pragma unroll
        for (int n = 0; n < 4; ++n) acc[m][n] = (f32x4){0.f,0.f,0.f,0.f};

    for (int kt = 0; kt < K; kt += 32) {
        __syncthreads();
        #pragma unroll
        for (int j = 0; j < 4; ++j) {
            uint4 q = *(const uint4*)(ag + kt + 4*j);
            uint32_t h0 = __builtin_amdgcn_perm(q.y, q.x, 0x05040100u);
            uint32_t h1 = __builtin_amdgcn_perm(q.w, q.z, 0x05040100u);
            uint32_t l0 = __builtin_amdgcn_perm(q.y, q.x, 0x07060302u);
            uint32_t l1 = __builtin_amdgcn_perm(q.w, q.z, 0x07060302u);
            int kx = sbase + ((k0 + 4*j) ^ swz);
            *(uint2*)&sAh[kx] = make_uint2(h0, h1);
            *(uint2*)&sAl[kx] = make_uint2(l0, l1);
        }
        #pragma unroll
        for (int j = 0; j < 4; ++j) {
            uint4 q = *(const uint4*)(bg + kt + 4*j);
            uint32_t h0 = __builtin_amdgcn_perm(q.y, q.x, 0x05040100u);
            uint32_t h1 = __builtin_amdgcn_perm(q.w, q.z, 0x05040100u);
            uint32_t l0 = __builtin_amdgcn_perm(q.y, q.x, 0x07060302u);
            uint32_t l1 = __builtin_amdgcn_perm(q.w, q.z, 0x07060302u);
            int kx = sbase + ((k0 + 4*j) ^ swz);
            *(uint2*)&sBh[kx] = make_uint2(h0, h1);
            *(uint2*)&sBl[kx] = make_uint2(l0, l1);
        }
        __syncthreads();

        f16x8 ah[4], al[4], bh[4], bl[4];
        #pragma unroll
        for (int m = 0; m < 4; ++m) {
            ah[m] = *(const f16x8*)&sAh[aoff[m]];
            al[m] = *(const f16x8*)&sAl[aoff[m]];
        }
        #pragma unroll
        for (int n = 0; n < 4; ++n) {
            bh[n] = *(const f16x8*)&sBh[boff[n]];
            bl[n] = *(const f16x8*)&sBl[boff[n]];
        }
        #pragma unroll
        for (int m = 0; m < 4; ++m)
            #pragma unroll
            for (int n = 0; n < 4; ++n) {
                acc[m][n] = __builtin_amdgcn_mfma_f32_16x16x32_f16(al[m], bh[n], acc[m][n], 0, 0, 0);
                acc[m][n] = __builtin_amdgcn_mfma_f32_16x16x32_f16(ah[m], bl[n], acc[m][n], 0, 0, 0);
                acc[m][n] = __builtin_amdgcn_mfma_f32_16x16x32_f16(ah[m], bh[n], acc[m][n], 0, 0, 0);
            }
    }

    #pragma unroll
    for (int n = 0; n < 4; ++n) {
        int col = bn*128 + wn*64 + n*16 + lr;
        float bb = bias[col];
        #pragma unroll
        for (int m = 0; m < 4; ++m) {
            int row0 = bm*128 + wm*64 + m*16 + lg*4;
            #pragma unroll
            for (int q = 0; q < 4; ++q) {
                float v = acc[m][n][q] + bb;
                if (relu) v = fmaxf(v, 0.f);
                size_t idx = (size_t)(row0 + q) * N + col;
                if (Opk) Opk[idx] = packsplit(v);
                if (Of)  Of[idx]  = v;
            }
        }
    }
}

// ---------------------------------------------------------------------------
// fp32 GEMM (rescore pass)
// ---------------------------------------------------------------------------
#define BM 128
#define BN 128
#define BK 16

__global__ __launch_bounds__(256) void k_gemm(
    const float* __restrict__ A, const float* __restrict__ W,
    const float* __restrict__ bias, float* __restrict__ C,
    int M, int K, int Nn, int relu)
{
    __shared__ float As[BK][BM + 4];
    __shared__ float Bs[BK][BN];
    const int tid = threadIdx.x;
    const int bm = blockIdx.y, bn = blockIdx.x;
    const int tr = tid >> 4, tc = tid & 15;
    const int ar0 = tid >> 2, ac0 = (tid & 3) * 4;
    const int bk0 = tid >> 5, bn0 = (tid & 31) * 4;
    const float* Ab = A + (size_t)bm * BM * K;
    const float* Wb = W + (size_t)bn * BN;

    float acc[8][8];
    #pragma unroll
    for (int i = 0; i < 8; ++i)
        #pragma unroll
        for (int j = 0; j < 8; ++j) acc[i][j] = 0.f;

    for (int k0 = 0; k0 < K; k0 += BK) {
        float4 a0 = *(const float4*)(Ab + (size_t)ar0*K      + k0 + ac0);
        float4 a1 = *(const float4*)(Ab + (size_t)(ar0+64)*K + k0 + ac0);
        float4 w0 = *(const float4*)(Wb + (size_t)(k0+bk0  )*Nn + bn0);
        float4 w1 = *(const float4*)(Wb + (size_t)(k0+bk0+8)*Nn + bn0);
        As[ac0+0][ar0]    = a0.x; As[ac0+1][ar0]    = a0.y;
        As[ac0+2][ar0]    = a0.z; As[ac0+3][ar0]    = a0.w;
        As[ac0+0][ar0+64] = a1.x; As[ac0+1][ar0+64] = a1.y;
        As[ac0+2][ar0+64] = a1.z; As[ac0+3][ar0+64] = a1.w;
        *(float4*)&Bs[bk0  ][bn0] = w0;
        *(float4*)&Bs[bk0+8][bn0] = w1;
        __syncthreads();
        #pragma unroll
        for (int kk = 0; kk < BK; ++kk) {
            float4 av0 = *(const float4*)&As[kk][tr*8];
            float4 av1 = *(const float4*)&As[kk][tr*8+4];
            float4 bv0 = *(const float4*)&Bs[kk][tc*8];
            float4 bv1 = *(const float4*)&Bs[kk][tc*8+4];
            float a[8] = {av0.x,av0.y,av0.z,av0.w, av1.x,av1.y,av1.z,av1.w};
            float b[8] = {bv0.x,bv0.y,bv0.z,bv0.w, bv1.x,bv1.y,bv1.z,bv1.w};
            #pragma unroll
            for (int i = 0; i < 8; ++i)
                #pragma unroll
                for (int j = 0; j < 8; ++j)
                    acc[i][j] = fmaf(a[i], b[j], acc[i][j]);
        }
        __syncthreads();
    }

    float bl[8];
    #pragma unroll
    for (int j = 0; j < 8; ++j) bl[j] = bias[(size_t)bn*BN + tc*8 + j];
    #pragma unroll
    for (int i = 0; i < 8; ++i) {
        int row = bm*BM + tr*8 + i;
        float v[8];
        #pragma unroll
        for (int j = 0; j < 8; ++j) {
            float x = acc[i][j] + bl[j];
            v[j] = relu ? fmaxf(x, 0.f) : x;
        }
        float4* cp = (float4*)(C + (size_t)row*Nn + bn*BN + tc*8);
        cp[0] = make_float4(v[0],v[1],v[2],v[3]);
        cp[1] = make_float4(v[4],v[5],v[6],v[7]);
    }
}

// ---------------------------------------------------------------------------
// score = T4[row,:384] . hw2 + hb2
// ---------------------------------------------------------------------------
__global__ __launch_bounds__(256) void k_score(
    const float* __restrict__ T4, const float* __restrict__ hw2,
    const float* __restrict__ hb2, float* __restrict__ scores, int M)
{
    int w = (blockIdx.x * 256 + threadIdx.x) >> 6;
    int lane = threadIdx.x & 63;
    if (w >= M) return;
    const float* row = T4 + (size_t)w * 384;
    float s = 0.f;
    #pragma unroll
    for (int j = 0; j < 384; j += 64) s = fmaf(row[j + lane], hw2[j + lane], s);
    for (int o = 32; o > 0; o >>= 1) s += __shfl_down(s, o, 64);
    if (lane == 0) scores[w] = s + hb2[0];
}

// ---------------------------------------------------------------------------
// Stage 1: per-batch top-CAND by split scores via one bitonic sort.
// Composite key (desc sort): [sortable(score):32][~pos:32]
//   => value desc, then pos asc. Exactly the old iterative semantics.
// ---------------------------------------------------------------------------
#define TPAD 4096
__global__ __launch_bounds__(256) void k_topcand(
    const float* __restrict__ scores, const int* __restrict__ offs,
    int* __restrict__ cand_g, int* __restrict__ cand_p)
{
    __shared__ uint64_t key[TPAD];   // 32 KiB
    int b = blockIdx.x, t = threadIdx.x;
    int off = offs[b];
    int cnt = min(offs[b+1] - off, MAXPB);

    for (int i = t; i < TPAD; i += 256) {
        uint64_t k = 0;
        if (i < cnt)
            k = ((uint64_t)sortable(scores[off + i]) << 32) | (uint32_t)(~i);
        key[i] = k;
    }

    for (int ksz = 2; ksz <= TPAD; ksz <<= 1) {
        for (int j = ksz >> 1; j > 0; j >>= 1) {
            __syncthreads();
            for (int i = t; i < TPAD; i += 256) {
                int ix = i ^ j;
                if (ix > i) {
                    uint64_t a = key[i], c = key[ix];
                    bool up = (i & ksz) == 0;           // descending blocks
                    if (up ? (a < c) : (a > c)) { key[i] = c; key[ix] = a; }
                }
            }
        }
    }
    __syncthreads();

    if (t < CAND) {
        if (t < cnt) {
            int pos = (int)(~(uint32_t)key[t]);
            cand_g[b*CAND + t] = off + pos;
            cand_p[b*CAND + t] = pos;
        } else {
            cand_g[b*CAND + t] = -1;
            cand_p[b*CAND + t] = MAXPB + t;
        }
    }
}

// ---------------------------------------------------------------------------
// Stage 2: final top-MT of the CAND candidates by fp32 score via bitonic.
// Composite: [sortable(fscore):32][~pos:12][j:8]  (pos unique -> j never ties)
// ---------------------------------------------------------------------------
__global__ __launch_bounds__(256) void k_fsel(
    const float* __restrict__ fscores, const int* __restrict__ offs,
    const int* __restrict__ cand_g, const int* __restrict__ cand_p,
    const float* __restrict__ coords, const float* __restrict__ times,
    int* __restrict__ tok_src, float* __restrict__ out_cent,
    float* __restrict__ out_mask)
{
    __shared__ uint64_t key[256];
    int b = blockIdx.x, t = threadIdx.x;
    int cnt = min(offs[b+1] - offs[b], MAXPB);
    int cntc = min(cnt, CAND);

    uint64_t k = 0;
    if (t < cntc) {
        uint32_t s32 = sortable(fscores[b*CAND + t]);
        uint32_t pos = (uint32_t)cand_p[b*CAND + t];
        k = ((uint64_t)s32 << 32) | (((~pos) & 0xFFFu) << 8) | (uint32_t)t;
    }
    key[t] = k;

    for (int ksz = 2; ksz <= 256; ksz <<= 1) {
        for (int j = ksz >> 1; j > 0; j >>= 1) {
            __syncthreads();
            int ix = t ^ j;
            if (ix > t) {
                uint64_t a = key[t], c = key[ix];
                bool up = (t & ksz) == 0;
                if (up ? (a < c) : (a > c)) { key[t] = c; key[ix] = a; }
            }
        }
    }
    __syncthreads();

    if (t < MT) {
        if (t < cntc) {
            int j = (int)(key[t] & 0xFF);
            int row = b*CAND + j;
            int g = cand_g[row];
            tok_src[b*MT + t] = row;
            out_mask[b*MT + t] = 1.0f;
            *(float4*)&out_cent[(size_t)(b*MT + t) * 4] =
                make_float4(coords[(size_t)g*3+0], coords[(size_t)g*3+1],
                            coords[(size_t)g*3+2], times[g]);
        } else {
            tok_src[b*MT + t] = -1;
            out_mask[b*MT + t] = 0.0f;
            *(float4*)&out_cent[(size_t)(b*MT + t) * 4] = make_float4(0.f,0.f,0.f,0.f);
        }
    }
}

// gather tokens from candidate point_feats
__global__ __launch_bounds__(256) void k_tokens(const float* __restrict__ PFc,
                                                const int* __restrict__ tok_src,
                                                float* __restrict__ out)
{
    int i = blockIdx.x * 256 + threadIdx.x;   // 8192*192 float4
    int row = i / 192, c = i % 192;
    int src = tok_src[row];
    float4 v = make_float4(0.f,0.f,0.f,0.f);
    if (src >= 0) v = ((const float4*)PFc)[(size_t)src*192 + c];
    ((float4*)out)[(size_t)row*192 + c] = v;
}

// ---------------------------------------------------------------------------
extern "C" void kernel_launch(void* const* d_in, const int* in_sizes, int n_in,
                              void* d_out, int out_size, void* d_ws, size_t ws_size,
                              hipStream_t stream)
{
    const float* coords = (const float*)d_in[0];
    const float* feats  = (const float*)d_in[1];
    const float* times  = (const float*)d_in[2];
    const int*   bids   = (const int*)  d_in[3];
    const float* ln_g = (const float*)d_in[4];
    const float* ln_b = (const float*)d_in[5];
    const float* sw1  = (const float*)d_in[6];
    const float* sb1  = (const float*)d_in[7];
    const float* sw2  = (const float*)d_in[8];
    const float* sb2  = (const float*)d_in[9];
    const float* mw1  = (const float*)d_in[10];
    const float* mb1  = (const float*)d_in[11];
    const float* mw2  = (const float*)d_in[12];
    const float* mb2  = (const float*)d_in[13];
    const float* mw3  = (const float*)d_in[14];
    const float* mb3  = (const float*)d_in[15];
    const float* mw4  = (const float*)d_in[16];
    const float* mb4  = (const float*)d_in[17];
    const float* hw1  = (const float*)d_in[18];
    const float* hb1  = (const float*)d_in[19];
    const float* hw2  = (const float*)d_in[20];
    const float* hb2  = (const float*)d_in[21];

    float* out_tok  = (float*)d_out;
    float* out_cent = out_tok + (size_t)NB*MT*TD;
    float* out_mask = out_cent + (size_t)NB*MT*4;

    char* wsb = (char*)d_ws;
    size_t off = 0;
    auto alloc = [&](size_t bytes) {
        char* p = wsb + off;
        off = (off + bytes + 255) & ~(size_t)255;
        return p;
    };
    int*      offs    = (int*)     alloc((NB + 1) * 4);
    float*    scores  = (float*)   alloc((size_t)NPTS * 4);
    float*    fscores = (float*)   alloc((size_t)MC * 4);
    int*      cand_g  = (int*)     alloc((size_t)MC * 4);
    int*      cand_p  = (int*)     alloc((size_t)MC * 4);
    int*      tok_src = (int*)     alloc((size_t)NB * MT * 4);
    uint32_t* wt1pk   = (uint32_t*)alloc((size_t)96  * 256 * 4);
    uint32_t* wt2pk   = (uint32_t*)alloc((size_t)256 * 512 * 4);
    uint32_t* wt3pk   = (uint32_t*)alloc((size_t)512 * 768 * 4);
    uint32_t* wt4pk   = (uint32_t*)alloc((size_t)768 * 768 * 4);
    uint32_t* ht1pk   = (uint32_t*)alloc((size_t)768 * 384 * 4);
    size_t base = off;

    int Nc = MC;                                    // floor: rescore needs MC rows
    const int cands[3] = {32768, 16384, MC};
    for (int ci = 0; ci < 3; ++ci) {
        size_t need = base + (size_t)cands[ci] * (96+256+512+768+768) * 4 + 6*256;
        if (need <= ws_size) { Nc = cands[ci]; break; }
    }
    char* X96b = alloc((size_t)Nc * 96  * 4);
    char* H1b  = alloc((size_t)Nc * 256 * 4);
    char* H2b  = alloc((size_t)Nc * 512 * 4);
    char* H3b  = alloc((size_t)Nc * 768 * 4);
    char* PFb  = alloc((size_t)Nc * 768 * 4);

    // ---------- setup ----------
    k_counts<<<1, 128, 0, stream>>>(bids, offs);
    k_splitw<<<(96*256 +255)/256, 256, 0, stream>>>(mw1, wt1pk,  96, 256);
    k_splitw<<<(256*512+255)/256, 256, 0, stream>>>(mw2, wt2pk, 256, 512);
    k_splitw<<<(512*768+255)/256, 256, 0, stream>>>(mw3, wt3pk, 512, 768);
    k_splitw<<<(768*768+255)/256, 256, 0, stream>>>(mw4, wt4pk, 768, 768);
    k_splitw<<<(768*384+255)/256, 256, 0, stream>>>(hw1, ht1pk, 768, 384);

    // ---------- stage 1: split-MFMA scoring over all points ----------
    {
        uint32_t* X96pk = (uint32_t*)X96b;
        uint32_t* H1pk  = (uint32_t*)H1b;
        uint32_t* H2pk  = (uint32_t*)H2b;
        uint32_t* H3pk  = (uint32_t*)H3b;
        uint32_t* PFpk  = (uint32_t*)PFb;
        float*    T4    = (float*)H2b;     // H2 dead by head time; 384f <= 512u32
        for (int p0 = 0; p0 < NPTS; p0 += Nc) {
            int Mi = min(Nc, NPTS - p0);
            k_x96pk<<<(Mi+255)/256, 256, 0, stream>>>(coords, feats, times, ln_g, ln_b,
                                                      sw1, sb1, sw2, sb2, p0, Mi, X96pk);
            k_mgemm<<<dim3(2, Mi/128), 256, 0, stream>>>(X96pk, wt1pk, mb1, H1pk, nullptr, Mi,  96, 256, 1);
            k_mgemm<<<dim3(4, Mi/128), 256, 0, stream>>>(H1pk,  wt2pk, mb2, H2pk, nullptr, Mi, 256, 512, 1);
            k_mgemm<<<dim3(6, Mi/128), 256, 0, stream>>>(H2pk,  wt3pk, mb3, H3pk, nullptr, Mi, 512, 768, 1);
            k_mgemm<<<dim3(6, Mi/128), 256, 0, stream>>>(H3pk,  wt4pk, mb4, PFpk, nullptr, Mi, 768, 768, 0);
            k_mgemm<<<dim3(3, Mi/128), 256, 0, stream>>>(PFpk,  ht1pk, hb1, nullptr, T4,   Mi, 768, 384, 1);
            k_score<<<(Mi+3)/4, 256, 0, stream>>>(T4, hw2, hb2, scores + p0, Mi);
        }
    }

    // ---------- stage 2: capture top-CAND per batch (bitonic) ----------
    k_topcand<<<NB, 256, 0, stream>>>(scores, offs, cand_g, cand_p);

    // ---------- stage 3: fp32 rescore of candidates ----------
    {
        float* X96 = (float*)X96b;
        float* H1  = (float*)H1b;
        float* H2  = (float*)H2b;
        float* H3  = (float*)H3b;
        float* PFc = (float*)PFb;
        float* T4  = (float*)H2b;          // H2 dead by head time
        k_x96f<<<MC/256, 256, 0, stream>>>(coords, feats, times, ln_g, ln_b,
                                           sw1, sb1, sw2, sb2, cand_g, MC, X96);
        k_gemm<<<dim3(2, MC/128), 256, 0, stream>>>(X96, mw1, mb1, H1, MC,  96, 256, 1);
        k_gemm<<<dim3(4, MC/128), 256, 0, stream>>>(H1,  mw2, mb2, H2, MC, 256, 512, 1);
        k_gemm<<<dim3(6, MC/128), 256, 0, stream>>>(H2,  mw3, mb3, H3, MC, 512, 768, 1);
        k_gemm<<<dim3(6, MC/128), 256, 0, stream>>>(H3,  mw4, mb4, PFc, MC, 768, 768, 0);
        k_gemm<<<dim3(3, MC/128), 256, 0, stream>>>(PFc, hw1, hb1, T4, MC, 768, 384, 1);
        k_score<<<MC/4, 256, 0, stream>>>(T4, hw2, hb2, fscores, MC);

        // ---------- stage 4: final top-128 per batch (bitonic) ----------
        k_fsel<<<NB, 256, 0, stream>>>(fscores, offs, cand_g, cand_p,
                                       coords, times, tok_src, out_cent, out_mask);
        k_tokens<<<(NB*MT*192)/256, 256, 0, stream>>>(PFc, tok_src, out_tok);
    }
}

// Round 5
// 1453.849 us; speedup vs baseline: 4.2869x; 1.6512x over previous
//
#include <hip/hip_runtime.h>
#include <cstdint>

#define NPTS 131072
#define NB 64
#define MAXPB 2560
#define MT 128
#define TD 768
#define CAND 160
#define MC (NB * CAND)   // 10240 candidate rows

typedef _Float16 f16;
typedef _Float16 f16x8 __attribute__((ext_vector_type(8)));
typedef float f32x4 __attribute__((ext_vector_type(4)));

__device__ __forceinline__ uint32_t pk2(float a, float b) {
    f16 ha = (f16)a, hb = (f16)b;
    return (uint32_t)__builtin_bit_cast(unsigned short, ha) |
           ((uint32_t)__builtin_bit_cast(unsigned short, hb) << 16);
}

// float -> order-preserving u32 (unsigned asc == float asc)
__device__ __forceinline__ uint32_t sortable(float f) {
    uint32_t u = __builtin_bit_cast(uint32_t, f);
    return u ^ (uint32_t)(((int32_t)u >> 31) | 0x80000000);
}

// ---------------------------------------------------------------------------
// offsets via binary search on sorted batch_ids
// ---------------------------------------------------------------------------
__global__ void k_counts(const int* __restrict__ bids, int* __restrict__ offs)
{
    int b = threadIdx.x;
    if (b > NB) return;
    int lo = 0, hi = NPTS;
    while (lo < hi) { int mid = (lo + hi) >> 1; if (bids[mid] < b) lo = mid + 1; else hi = mid; }
    offs[b] = lo;
}

// ---------------------------------------------------------------------------
// weight cast: W[K][N] fp32 -> Wt[N][Kpad] f16 (zero-padded K)
// ---------------------------------------------------------------------------
__global__ __launch_bounds__(256) void k_cvtw(const float* __restrict__ W,
                                              unsigned short* __restrict__ out,
                                              int K, int N, int Kpad)
{
    int i = blockIdx.x * 256 + threadIdx.x;
    if (i >= N * Kpad) return;
    int n = i / Kpad, k = i % Kpad;
    f16 v = (f16)0.f;
    if (k < K) v = (f16)W[(size_t)k * N + n];
    out[i] = __builtin_bit_cast(unsigned short, v);
}

// ---------------------------------------------------------------------------
// Per-point front-end, f16 output [M][128] = [feat32, sp64, pad32]
// ---------------------------------------------------------------------------
__global__ __launch_bounds__(256) void k_x96h(
    const float* __restrict__ coords, const float* __restrict__ feats,
    const float* __restrict__ times,
    const float* __restrict__ ln_g, const float* __restrict__ ln_b,
    const float* __restrict__ sw1, const float* __restrict__ sb1,
    const float* __restrict__ sw2, const float* __restrict__ sb2,
    int p0, int M, unsigned short* __restrict__ X)
{
    __shared__ float w1[256], w2[4096], b1[64], b2[64];
    int t = threadIdx.x;
    w1[t] = sw1[t];
    for (int i = t; i < 4096; i += 256) w2[i] = sw2[i];
    if (t < 64) { b1[t] = sb1[t]; b2[t] = sb2[t]; }
    __syncthreads();

    int r = blockIdx.x * 256 + t;
    if (r >= M) return;
    int p = p0 + r;
    unsigned short* out = X + (size_t)r * 128;

    float x0 = coords[(size_t)p*3+0], x1 = coords[(size_t)p*3+1];
    float x2 = coords[(size_t)p*3+2], x3 = times[p];
    float mu = 0.25f*(x0+x1+x2+x3);
    float d0 = x0-mu, d1 = x1-mu, d2 = x2-mu, d3 = x3-mu;
    float var = 0.25f*(d0*d0+d1*d1+d2*d2+d3*d3);
    float inv = 1.0f / sqrtf(var + 1e-5f);
    float xn0 = d0*inv*ln_g[0]+ln_b[0];
    float xn1 = d1*inv*ln_g[1]+ln_b[1];
    float xn2 = d2*inv*ln_g[2]+ln_b[2];
    float xn3 = d3*inv*ln_g[3]+ln_b[3];

    float s1[64];
    #pragma unroll
    for (int j = 0; j < 64; ++j) {
        float a = b1[j];
        a = fmaf(xn0, w1[j],       a);
        a = fmaf(xn1, w1[64 + j],  a);
        a = fmaf(xn2, w1[128 + j], a);
        a = fmaf(xn3, w1[192 + j], a);
        s1[j] = fmaxf(a, 0.f);
    }
    #pragma unroll
    for (int j = 0; j < 32; j += 8) {
        float4 f0 = *(const float4*)(feats + (size_t)p*32 + j);
        float4 f1 = *(const float4*)(feats + (size_t)p*32 + j + 4);
        uint4 u = make_uint4(pk2(f0.x,f0.y), pk2(f0.z,f0.w),
                             pk2(f1.x,f1.y), pk2(f1.z,f1.w));
        *(uint4*)(out + j) = u;
    }
    for (int j0 = 0; j0 < 64; j0 += 8) {
        float a[8];
        #pragma unroll
        for (int i = 0; i < 8; ++i) a[i] = b2[j0+i];
        #pragma unroll
        for (int k = 0; k < 64; ++k) {
            float s = s1[k];
            const float* wr = &w2[k*64 + j0];
            #pragma unroll
            for (int i = 0; i < 8; ++i) a[i] = fmaf(s, wr[i], a[i]);
        }
        #pragma unroll
        for (int i = 0; i < 8; ++i) a[i] = fmaxf(a[i], 0.f);
        uint4 u = make_uint4(pk2(a[0],a[1]), pk2(a[2],a[3]),
                             pk2(a[4],a[5]), pk2(a[6],a[7]));
        *(uint4*)(out + 32 + j0) = u;
    }
    uint4 z = make_uint4(0,0,0,0);
    *(uint4*)(out + 96)  = z;
    *(uint4*)(out + 104) = z;
    *(uint4*)(out + 112) = z;
    *(uint4*)(out + 120) = z;
}

// ---------------------------------------------------------------------------
// Per-point front-end, FP32 output, gather variant (rescore pass)
// ---------------------------------------------------------------------------
__global__ __launch_bounds__(256) void k_x96f(
    const float* __restrict__ coords, const float* __restrict__ feats,
    const float* __restrict__ times,
    const float* __restrict__ ln_g, const float* __restrict__ ln_b,
    const float* __restrict__ sw1, const float* __restrict__ sb1,
    const float* __restrict__ sw2, const float* __restrict__ sb2,
    const int* __restrict__ sel, int M, float* __restrict__ X96)
{
    __shared__ float w1[256], w2[4096], b1[64], b2[64];
    int t = threadIdx.x;
    w1[t] = sw1[t];
    for (int i = t; i < 4096; i += 256) w2[i] = sw2[i];
    if (t < 64) { b1[t] = sb1[t]; b2[t] = sb2[t]; }
    __syncthreads();

    int r = blockIdx.x * 256 + t;
    if (r >= M) return;
    int p = sel[r];
    float* out = X96 + (size_t)r * 96;
    if (p < 0) {
        for (int j = 0; j < 96; j += 4) *(float4*)(out + j) = make_float4(0.f,0.f,0.f,0.f);
        return;
    }
    float x0 = coords[(size_t)p*3+0], x1 = coords[(size_t)p*3+1];
    float x2 = coords[(size_t)p*3+2], x3 = times[p];
    float mu = 0.25f*(x0+x1+x2+x3);
    float d0 = x0-mu, d1 = x1-mu, d2 = x2-mu, d3 = x3-mu;
    float var = 0.25f*(d0*d0+d1*d1+d2*d2+d3*d3);
    float inv = 1.0f / sqrtf(var + 1e-5f);
    float xn0 = d0*inv*ln_g[0]+ln_b[0];
    float xn1 = d1*inv*ln_g[1]+ln_b[1];
    float xn2 = d2*inv*ln_g[2]+ln_b[2];
    float xn3 = d3*inv*ln_g[3]+ln_b[3];

    float s1[64];
    #pragma unroll
    for (int j = 0; j < 64; ++j) {
        float a = b1[j];
        a = fmaf(xn0, w1[j],       a);
        a = fmaf(xn1, w1[64 + j],  a);
        a = fmaf(xn2, w1[128 + j], a);
        a = fmaf(xn3, w1[192 + j], a);
        s1[j] = fmaxf(a, 0.f);
    }
    #pragma unroll
    for (int j = 0; j < 32; j += 4)
        *(float4*)(out + j) = *(const float4*)(feats + (size_t)p*32 + j);

    for (int j0 = 0; j0 < 64; j0 += 4) {
        float a0 = b2[j0+0], a1 = b2[j0+1], a2 = b2[j0+2], a3 = b2[j0+3];
        #pragma unroll
        for (int k = 0; k < 64; ++k) {
            float s = s1[k];
            const float* wr = &w2[k*64 + j0];
            a0 = fmaf(s, wr[0], a0);
            a1 = fmaf(s, wr[1], a1);
            a2 = fmaf(s, wr[2], a2);
            a3 = fmaf(s, wr[3], a3);
        }
        *(float4*)(out + 32 + j0) =
            make_float4(fmaxf(a0,0.f), fmaxf(a1,0.f), fmaxf(a2,0.f), fmaxf(a3,0.f));
    }
}

// ---------------------------------------------------------------------------
// Pure-f16 MFMA GEMM (scoring pass): O[M][N] f16 = act(A[M][K] @ Bt[N][K]^T + b)
// 128x128x64 tile, 4 waves (2x2), 16x16x32 f16 MFMA, padded-row LDS (72 f16).
// ---------------------------------------------------------------------------
__global__ __launch_bounds__(256, 2) void k_hgemm(
    const unsigned short* __restrict__ A, const unsigned short* __restrict__ Bt,
    const float* __restrict__ bias, unsigned short* __restrict__ O,
    int M, int K, int N, int relu)
{
    __shared__ unsigned short sA[128*72];
    __shared__ unsigned short sB[128*72];
    const int tid = threadIdx.x;
    const int bm = blockIdx.y, bn = blockIdx.x;
    const int lane = tid & 63, w = tid >> 6;
    const int wm = w >> 1, wn = w & 1;
    const int lr = lane & 15, lg = lane >> 4;

    const int sr = tid >> 1, hb = tid & 1;          // row, k-half (32 f16)
    const unsigned short* ag = A  + (size_t)(bm*128 + sr) * K + hb*32;
    const unsigned short* bg = Bt + (size_t)(bn*128 + sr) * K + hb*32;
    const int wof = sr*72 + hb*32;

    int aoff[4], boff[4];
    #pragma unroll
    for (int m = 0; m < 4; ++m) aoff[m] = (wm*64 + m*16 + lr)*72 + lg*8;
    #pragma unroll
    for (int n = 0; n < 4; ++n) boff[n] = (wn*64 + n*16 + lr)*72 + lg*8;

    f32x4 acc[4][4];
    #pragma unroll
    for (int m = 0; m < 4; ++m)
        #pragma unroll
        for (int n = 0; n < 4; ++n) acc[m][n] = (f32x4){0.f,0.f,0.f,0.f};

    for (int kt = 0; kt < K; kt += 64) {
        uint4 qa0 = *(const uint4*)(ag + kt);
        uint4 qa1 = *(const uint4*)(ag + kt + 8);
        uint4 qa2 = *(const uint4*)(ag + kt + 16);
        uint4 qa3 = *(const uint4*)(ag + kt + 24);
        uint4 qb0 = *(const uint4*)(bg + kt);
        uint4 qb1 = *(const uint4*)(bg + kt + 8);
        uint4 qb2 = *(const uint4*)(bg + kt + 16);
        uint4 qb3 = *(const uint4*)(bg + kt + 24);
        __syncthreads();                      // prev iter's reads complete
        *(uint4*)(sA + wof)      = qa0;
        *(uint4*)(sA + wof + 8)  = qa1;
        *(uint4*)(sA + wof + 16) = qa2;
        *(uint4*)(sA + wof + 24) = qa3;
        *(uint4*)(sB + wof)      = qb0;
        *(uint4*)(sB + wof + 8)  = qb1;
        *(uint4*)(sB + wof + 16) = qb2;
        *(uint4*)(sB + wof + 24) = qb3;
        __syncthreads();

        #pragma unroll
        for (int kk = 0; kk < 64; kk += 32) {
            f16x8 af[4], bf[4];
            #pragma unroll
            for (int m = 0; m < 4; ++m) af[m] = *(const f16x8*)&sA[aoff[m] + kk];
            #pragma unroll
            for (int n = 0; n < 4; ++n) bf[n] = *(const f16x8*)&sB[boff[n] + kk];
            #pragma unroll
            for (int m = 0; m < 4; ++m)
                #pragma unroll
                for (int n = 0; n < 4; ++n)
                    acc[m][n] = __builtin_amdgcn_mfma_f32_16x16x32_f16(af[m], bf[n], acc[m][n], 0, 0, 0);
        }
    }

    #pragma unroll
    for (int n = 0; n < 4; ++n) {
        int col = bn*128 + wn*64 + n*16 + lr;
        float bb = bias[col];
        #pragma unroll
        for (int m = 0; m < 4; ++m) {
            int row0 = bm*128 + wm*64 + m*16 + lg*4;
            #pragma unroll
            for (int q = 0; q < 4; ++q) {
                float v = acc[m][n][q] + bb;
                if (relu) v = fmaxf(v, 0.f);
                f16 h = (f16)v;
                O[(size_t)(row0 + q) * N + col] = __builtin_bit_cast(unsigned short, h);
            }
        }
    }
}

// ---------------------------------------------------------------------------
// fp32 GEMM (rescore pass) — validated
// ---------------------------------------------------------------------------
#define BM 128
#define BN 128
#define BK 16

__global__ __launch_bounds__(256) void k_gemm(
    const float* __restrict__ A, const float* __restrict__ W,
    const float* __restrict__ bias, float* __restrict__ C,
    int M, int K, int Nn, int relu)
{
    __shared__ float As[BK][BM + 4];
    __shared__ float Bs[BK][BN];
    const int tid = threadIdx.x;
    const int bm = blockIdx.y, bn = blockIdx.x;
    const int tr = tid >> 4, tc = tid & 15;
    const int ar0 = tid >> 2, ac0 = (tid & 3) * 4;
    const int bk0 = tid >> 5, bn0 = (tid & 31) * 4;
    const float* Ab = A + (size_t)bm * BM * K;
    const float* Wb = W + (size_t)bn * BN;

    float acc[8][8];
    #pragma unroll
    for (int i = 0; i < 8; ++i)
        #pragma unroll
        for (int j = 0; j < 8; ++j) acc[i][j] = 0.f;

    for (int k0 = 0; k0 < K; k0 += BK) {
        float4 a0 = *(const float4*)(Ab + (size_t)ar0*K      + k0 + ac0);
        float4 a1 = *(const float4*)(Ab + (size_t)(ar0+64)*K + k0 + ac0);
        float4 w0 = *(const float4*)(Wb + (size_t)(k0+bk0  )*Nn + bn0);
        float4 w1 = *(const float4*)(Wb + (size_t)(k0+bk0+8)*Nn + bn0);
        As[ac0+0][ar0]    = a0.x; As[ac0+1][ar0]    = a0.y;
        As[ac0+2][ar0]    = a0.z; As[ac0+3][ar0]    = a0.w;
        As[ac0+0][ar0+64] = a1.x; As[ac0+1][ar0+64] = a1.y;
        As[ac0+2][ar0+64] = a1.z; As[ac0+3][ar0+64] = a1.w;
        *(float4*)&Bs[bk0  ][bn0] = w0;
        *(float4*)&Bs[bk0+8][bn0] = w1;
        __syncthreads();
        #pragma unroll
        for (int kk = 0; kk < BK; ++kk) {
            float4 av0 = *(const float4*)&As[kk][tr*8];
            float4 av1 = *(const float4*)&As[kk][tr*8+4];
            float4 bv0 = *(const float4*)&Bs[kk][tc*8];
            float4 bv1 = *(const float4*)&Bs[kk][tc*8+4];
            float a[8] = {av0.x,av0.y,av0.z,av0.w, av1.x,av1.y,av1.z,av1.w};
            float b[8] = {bv0.x,bv0.y,bv0.z,bv0.w, bv1.x,bv1.y,bv1.z,bv1.w};
            #pragma unroll
            for (int i = 0; i < 8; ++i)
                #pragma unroll
                for (int j = 0; j < 8; ++j)
                    acc[i][j] = fmaf(a[i], b[j], acc[i][j]);
        }
        __syncthreads();
    }

    float bl[8];
    #pragma unroll
    for (int j = 0; j < 8; ++j) bl[j] = bias[(size_t)bn*BN + tc*8 + j];
    #pragma unroll
    for (int i = 0; i < 8; ++i) {
        int row = bm*BM + tr*8 + i;
        float v[8];
        #pragma unroll
        for (int j = 0; j < 8; ++j) {
            float x = acc[i][j] + bl[j];
            v[j] = relu ? fmaxf(x, 0.f) : x;
        }
        float4* cp = (float4*)(C + (size_t)row*Nn + bn*BN + tc*8);
        cp[0] = make_float4(v[0],v[1],v[2],v[3]);
        cp[1] = make_float4(v[4],v[5],v[6],v[7]);
    }
}

// ---------------------------------------------------------------------------
// scores from f16 T4 (stage 1) and fp32 T4 (rescore)
// ---------------------------------------------------------------------------
__global__ __launch_bounds__(256) void k_scoreh(
    const unsigned short* __restrict__ T4, const float* __restrict__ hw2,
    const float* __restrict__ hb2, float* __restrict__ scores, int M)
{
    int wv = (blockIdx.x * 256 + threadIdx.x) >> 6;
    int lane = threadIdx.x & 63;
    if (wv >= M) return;
    const unsigned short* row = T4 + (size_t)wv * 384;
    float s = 0.f;
    #pragma unroll
    for (int j = 0; j < 384; j += 64) {
        f16 h = __builtin_bit_cast(f16, row[j + lane]);
        s = fmaf((float)h, hw2[j + lane], s);
    }
    for (int o = 32; o > 0; o >>= 1) s += __shfl_down(s, o, 64);
    if (lane == 0) scores[wv] = s + hb2[0];
}

__global__ __launch_bounds__(256) void k_score(
    const float* __restrict__ T4, const float* __restrict__ hw2,
    const float* __restrict__ hb2, float* __restrict__ scores, int M)
{
    int wv = (blockIdx.x * 256 + threadIdx.x) >> 6;
    int lane = threadIdx.x & 63;
    if (wv >= M) return;
    const float* row = T4 + (size_t)wv * 384;
    float s = 0.f;
    #pragma unroll
    for (int j = 0; j < 384; j += 64) s = fmaf(row[j + lane], hw2[j + lane], s);
    for (int o = 32; o > 0; o >>= 1) s += __shfl_down(s, o, 64);
    if (lane == 0) scores[wv] = s + hb2[0];
}

// ---------------------------------------------------------------------------
// Stage 1 select: per-batch top-CAND via bitonic sort.
// Key: [sortable(score):32][~pos:32]  => value desc, pos asc.
// ---------------------------------------------------------------------------
#define TPAD 4096
__global__ __launch_bounds__(256) void k_topcand(
    const float* __restrict__ scores, const int* __restrict__ offs,
    int* __restrict__ cand_g, int* __restrict__ cand_p)
{
    __shared__ uint64_t key[TPAD];   // 32 KiB
    int b = blockIdx.x, t = threadIdx.x;
    int off = offs[b];
    int cnt = min(offs[b+1] - off, MAXPB);

    for (int i = t; i < TPAD; i += 256) {
        uint64_t k = 0;
        if (i < cnt)
            k = ((uint64_t)sortable(scores[off + i]) << 32) | (uint32_t)(~i);
        key[i] = k;
    }

    for (int ksz = 2; ksz <= TPAD; ksz <<= 1) {
        for (int j = ksz >> 1; j > 0; j >>= 1) {
            __syncthreads();
            for (int i = t; i < TPAD; i += 256) {
                int ix = i ^ j;
                if (ix > i) {
                    uint64_t a = key[i], c = key[ix];
                    bool up = (i & ksz) == 0;
                    if (up ? (a < c) : (a > c)) { key[i] = c; key[ix] = a; }
                }
            }
        }
    }
    __syncthreads();

    if (t < CAND) {
        if (t < cnt) {
            int pos = (int)(~(uint32_t)key[t]);
            cand_g[b*CAND + t] = off + pos;
            cand_p[b*CAND + t] = pos;
        } else {
            cand_g[b*CAND + t] = -1;
            cand_p[b*CAND + t] = MAXPB + t;
        }
    }
}

// ---------------------------------------------------------------------------
// Stage 2: final top-MT by fp32 score via bitonic.
// Key: [sortable(fscore):32][~pos:12][j:8]
// ---------------------------------------------------------------------------
__global__ __launch_bounds__(256) void k_fsel(
    const float* __restrict__ fscores, const int* __restrict__ offs,
    const int* __restrict__ cand_g, const int* __restrict__ cand_p,
    const float* __restrict__ coords, const float* __restrict__ times,
    int* __restrict__ tok_src, float* __restrict__ out_cent,
    float* __restrict__ out_mask)
{
    __shared__ uint64_t key[256];
    int b = blockIdx.x, t = threadIdx.x;
    int cnt = min(offs[b+1] - offs[b], MAXPB);
    int cntc = min(cnt, CAND);

    uint64_t k = 0;
    if (t < cntc) {
        uint32_t s32 = sortable(fscores[b*CAND + t]);
        uint32_t pos = (uint32_t)cand_p[b*CAND + t];
        k = ((uint64_t)s32 << 32) | (((~pos) & 0xFFFu) << 8) | (uint32_t)t;
    }
    key[t] = k;

    for (int ksz = 2; ksz <= 256; ksz <<= 1) {
        for (int j = ksz >> 1; j > 0; j >>= 1) {
            __syncthreads();
            int ix = t ^ j;
            if (ix > t) {
                uint64_t a = key[t], c = key[ix];
                bool up = (t & ksz) == 0;
                if (up ? (a < c) : (a > c)) { key[t] = c; key[ix] = a; }
            }
        }
    }
    __syncthreads();

    if (t < MT) {
        if (t < cntc) {
            int j = (int)(key[t] & 0xFF);
            int row = b*CAND + j;
            int g = cand_g[row];
            tok_src[b*MT + t] = row;
            out_mask[b*MT + t] = 1.0f;
            *(float4*)&out_cent[(size_t)(b*MT + t) * 4] =
                make_float4(coords[(size_t)g*3+0], coords[(size_t)g*3+1],
                            coords[(size_t)g*3+2], times[g]);
        } else {
            tok_src[b*MT + t] = -1;
            out_mask[b*MT + t] = 0.0f;
            *(float4*)&out_cent[(size_t)(b*MT + t) * 4] = make_float4(0.f,0.f,0.f,0.f);
        }
    }
}

// gather tokens from candidate point_feats
__global__ __launch_bounds__(256) void k_tokens(const float* __restrict__ PFc,
                                                const int* __restrict__ tok_src,
                                                float* __restrict__ out)
{
    int i = blockIdx.x * 256 + threadIdx.x;   // 8192*192 float4
    int row = i / 192, c = i % 192;
    int src = tok_src[row];
    float4 v = make_float4(0.f,0.f,0.f,0.f);
    if (src >= 0) v = ((const float4*)PFc)[(size_t)src*192 + c];
    ((float4*)out)[(size_t)row*192 + c] = v;
}

// ---------------------------------------------------------------------------
extern "C" void kernel_launch(void* const* d_in, const int* in_sizes, int n_in,
                              void* d_out, int out_size, void* d_ws, size_t ws_size,
                              hipStream_t stream)
{
    const float* coords = (const float*)d_in[0];
    const float* feats  = (const float*)d_in[1];
    const float* times  = (const float*)d_in[2];
    const int*   bids   = (const int*)  d_in[3];
    const float* ln_g = (const float*)d_in[4];
    const float* ln_b = (const float*)d_in[5];
    const float* sw1  = (const float*)d_in[6];
    const float* sb1  = (const float*)d_in[7];
    const float* sw2  = (const float*)d_in[8];
    const float* sb2  = (const float*)d_in[9];
    const float* mw1  = (const float*)d_in[10];
    const float* mb1  = (const float*)d_in[11];
    const float* mw2  = (const float*)d_in[12];
    const float* mb2  = (const float*)d_in[13];
    const float* mw3  = (const float*)d_in[14];
    const float* mb3  = (const float*)d_in[15];
    const float* mw4  = (const float*)d_in[16];
    const float* mb4  = (const float*)d_in[17];
    const float* hw1  = (const float*)d_in[18];
    const float* hb1  = (const float*)d_in[19];
    const float* hw2  = (const float*)d_in[20];
    const float* hb2  = (const float*)d_in[21];

    float* out_tok  = (float*)d_out;
    float* out_cent = out_tok + (size_t)NB*MT*TD;
    float* out_mask = out_cent + (size_t)NB*MT*4;

    char* wsb = (char*)d_ws;
    size_t off = 0;
    auto alloc = [&](size_t bytes) {
        char* p = wsb + off;
        off = (off + bytes + 255) & ~(size_t)255;
        return p;
    };
    auto mx = [](size_t a, size_t b) { return a > b ? a : b; };

    int*   offs    = (int*)  alloc((NB + 1) * 4);
    float* scores  = (float*)alloc((size_t)NPTS * 4);
    float* fscores = (float*)alloc((size_t)MC * 4);
    int*   cand_g  = (int*)  alloc((size_t)MC * 4);
    int*   cand_p  = (int*)  alloc((size_t)MC * 4);
    int*   tok_src = (int*)  alloc((size_t)NB * MT * 4);
    unsigned short* wt1h = (unsigned short*)alloc((size_t)256 * 128 * 2);
    unsigned short* wt2h = (unsigned short*)alloc((size_t)512 * 256 * 2);
    unsigned short* wt3h = (unsigned short*)alloc((size_t)768 * 512 * 2);
    unsigned short* wt4h = (unsigned short*)alloc((size_t)768 * 768 * 2);
    unsigned short* ht1h = (unsigned short*)alloc((size_t)384 * 768 * 2);
    size_t base = off;

    int Nc = 8192;
    const int cands[3] = {32768, 16384, 8192};
    for (int ci = 0; ci < 3; ++ci) {
        size_t n = cands[ci];
        size_t need = base
            + mx(n*128*2, (size_t)MC*96*4)
            + mx(n*256*2, (size_t)MC*256*4)
            + mx(n*512*2, (size_t)MC*512*4)
            + 2 * mx(n*768*2, (size_t)MC*768*4)
            + 6*256;
        if (need <= ws_size) { Nc = (int)n; break; }
    }
    char* B0 = alloc(mx((size_t)Nc*128*2, (size_t)MC*96*4));
    char* B1 = alloc(mx((size_t)Nc*256*2, (size_t)MC*256*4));
    char* B2 = alloc(mx((size_t)Nc*512*2, (size_t)MC*512*4));
    char* B3 = alloc(mx((size_t)Nc*768*2, (size_t)MC*768*4));
    char* B4 = alloc(mx((size_t)Nc*768*2, (size_t)MC*768*4));

    // ---------- setup ----------
    k_counts<<<1, 128, 0, stream>>>(bids, offs);
    k_cvtw<<<(256*128+255)/256, 256, 0, stream>>>(mw1, wt1h,  96, 256, 128);
    k_cvtw<<<(512*256+255)/256, 256, 0, stream>>>(mw2, wt2h, 256, 512, 256);
    k_cvtw<<<(768*512+255)/256, 256, 0, stream>>>(mw3, wt3h, 512, 768, 512);
    k_cvtw<<<(768*768+255)/256, 256, 0, stream>>>(mw4, wt4h, 768, 768, 768);
    k_cvtw<<<(384*768+255)/256, 256, 0, stream>>>(hw1, ht1h, 768, 384, 768);

    // ---------- stage 1: pure-f16 MFMA scoring over all points ----------
    {
        unsigned short* X   = (unsigned short*)B0;   // [Nc][128]
        unsigned short* H1h = (unsigned short*)B1;   // [Nc][256]
        unsigned short* H2h = (unsigned short*)B2;   // [Nc][512]
        unsigned short* H3h = (unsigned short*)B3;   // [Nc][768]
        unsigned short* PFh = (unsigned short*)B4;   // [Nc][768]
        unsigned short* T4h = (unsigned short*)B2;   // [Nc][384], H2 dead by then
        for (int p0 = 0; p0 < NPTS; p0 += Nc) {
            int Mi = min(Nc, NPTS - p0);
            k_x96h<<<(Mi+255)/256, 256, 0, stream>>>(coords, feats, times, ln_g, ln_b,
                                                     sw1, sb1, sw2, sb2, p0, Mi, X);
            k_hgemm<<<dim3(2, Mi/128), 256, 0, stream>>>(X,   wt1h, mb1, H1h, Mi, 128, 256, 1);
            k_hgemm<<<dim3(4, Mi/128), 256, 0, stream>>>(H1h, wt2h, mb2, H2h, Mi, 256, 512, 1);
            k_hgemm<<<dim3(6, Mi/128), 256, 0, stream>>>(H2h, wt3h, mb3, H3h, Mi, 512, 768, 1);
            k_hgemm<<<dim3(6, Mi/128), 256, 0, stream>>>(H3h, wt4h, mb4, PFh, Mi, 768, 768, 0);
            k_hgemm<<<dim3(3, Mi/128), 256, 0, stream>>>(PFh, ht1h, hb1, T4h, Mi, 768, 384, 1);
            k_scoreh<<<(Mi+3)/4, 256, 0, stream>>>(T4h, hw2, hb2, scores + p0, Mi);
        }
    }

    // ---------- stage 2: capture top-CAND per batch (bitonic) ----------
    k_topcand<<<NB, 256, 0, stream>>>(scores, offs, cand_g, cand_p);

    // ---------- stage 3: fp32 rescore of candidates ----------
    {
        float* X96 = (float*)B0;
        float* H1  = (float*)B1;
        float* H2  = (float*)B2;
        float* H3  = (float*)B3;
        float* PFc = (float*)B4;
        float* T4  = (float*)B2;           // H2 dead by head time
        k_x96f<<<MC/256, 256, 0, stream>>>(coords, feats, times, ln_g, ln_b,
                                           sw1, sb1, sw2, sb2, cand_g, MC, X96);
        k_gemm<<<dim3(2, MC/128), 256, 0, stream>>>(X96, mw1, mb1, H1, MC,  96, 256, 1);
        k_gemm<<<dim3(4, MC/128), 256, 0, stream>>>(H1,  mw2, mb2, H2, MC, 256, 512, 1);
        k_gemm<<<dim3(6, MC/128), 256, 0, stream>>>(H2,  mw3, mb3, H3, MC, 512, 768, 1);
        k_gemm<<<dim3(6, MC/128), 256, 0, stream>>>(H3,  mw4, mb4, PFc, MC, 768, 768, 0);
        k_gemm<<<dim3(3, MC/128), 256, 0, stream>>>(PFc, hw1, hb1, T4, MC, 768, 384, 1);
        k_score<<<MC/4, 256, 0, stream>>>(T4, hw2, hb2, fscores, MC);

        // ---------- stage 4: final top-128 per batch (bitonic) ----------
        k_fsel<<<NB, 256, 0, stream>>>(fscores, offs, cand_g, cand_p,
                                       coords, times, tok_src, out_cent, out_mask);
        k_tokens<<<(NB*MT*192)/256, 256, 0, stream>>>(PFc, tok_src, out_tok);
    }
}

// Round 6
// 1406.879 us; speedup vs baseline: 4.4300x; 1.0334x over previous
//
#include <hip/hip_runtime.h>
#include <cstdint>

#define NPTS 131072
#define NB 64
#define MAXPB 2560
#define MT 128
#define TD 768
#define CAND 160
#define MC (NB * CAND)   // 10240 candidate rows

typedef _Float16 f16;
typedef _Float16 f16x8 __attribute__((ext_vector_type(8)));
typedef float f32x4 __attribute__((ext_vector_type(4)));

__device__ __forceinline__ uint32_t pk2(float a, float b) {
    f16 ha = (f16)a, hb = (f16)b;
    return (uint32_t)__builtin_bit_cast(unsigned short, ha) |
           ((uint32_t)__builtin_bit_cast(unsigned short, hb) << 16);
}

// float -> order-preserving u32 (unsigned asc == float asc)
__device__ __forceinline__ uint32_t sortable(float f) {
    uint32_t u = __builtin_bit_cast(uint32_t, f);
    return u ^ (uint32_t)(((int32_t)u >> 31) | 0x80000000);
}

// direct HBM -> LDS, 16B per lane. LDS dest = wave-uniform base + lane*16.
__device__ __forceinline__ void gload16(const void* g, void* l) {
    __builtin_amdgcn_global_load_lds(
        (const __attribute__((address_space(1))) uint32_t*)g,
        (__attribute__((address_space(3))) uint32_t*)l,
        16, 0, 0);
}

// ---------------------------------------------------------------------------
// offsets via binary search on sorted batch_ids
// ---------------------------------------------------------------------------
__global__ void k_counts(const int* __restrict__ bids, int* __restrict__ offs)
{
    int b = threadIdx.x;
    if (b > NB) return;
    int lo = 0, hi = NPTS;
    while (lo < hi) { int mid = (lo + hi) >> 1; if (bids[mid] < b) lo = mid + 1; else hi = mid; }
    offs[b] = lo;
}

// ---------------------------------------------------------------------------
// weight cast: W[K][N] fp32 -> Wt[N][Kpad] f16 (zero-padded K)
// ---------------------------------------------------------------------------
__global__ __launch_bounds__(256) void k_cvtw(const float* __restrict__ W,
                                              unsigned short* __restrict__ out,
                                              int K, int N, int Kpad)
{
    int i = blockIdx.x * 256 + threadIdx.x;
    if (i >= N * Kpad) return;
    int n = i / Kpad, k = i % Kpad;
    f16 v = (f16)0.f;
    if (k < K) v = (f16)W[(size_t)k * N + n];
    out[i] = __builtin_bit_cast(unsigned short, v);
}

// ---------------------------------------------------------------------------
// Per-point front-end, f16 output [M][128] = [feat32, sp64, pad32]
// ---------------------------------------------------------------------------
__global__ __launch_bounds__(256) void k_x96h(
    const float* __restrict__ coords, const float* __restrict__ feats,
    const float* __restrict__ times,
    const float* __restrict__ ln_g, const float* __restrict__ ln_b,
    const float* __restrict__ sw1, const float* __restrict__ sb1,
    const float* __restrict__ sw2, const float* __restrict__ sb2,
    int p0, int M, unsigned short* __restrict__ X)
{
    __shared__ float w1[256], w2[4096], b1[64], b2[64];
    int t = threadIdx.x;
    w1[t] = sw1[t];
    for (int i = t; i < 4096; i += 256) w2[i] = sw2[i];
    if (t < 64) { b1[t] = sb1[t]; b2[t] = sb2[t]; }
    __syncthreads();

    int r = blockIdx.x * 256 + t;
    if (r >= M) return;
    int p = p0 + r;
    unsigned short* out = X + (size_t)r * 128;

    float x0 = coords[(size_t)p*3+0], x1 = coords[(size_t)p*3+1];
    float x2 = coords[(size_t)p*3+2], x3 = times[p];
    float mu = 0.25f*(x0+x1+x2+x3);
    float d0 = x0-mu, d1 = x1-mu, d2 = x2-mu, d3 = x3-mu;
    float var = 0.25f*(d0*d0+d1*d1+d2*d2+d3*d3);
    float inv = 1.0f / sqrtf(var + 1e-5f);
    float xn0 = d0*inv*ln_g[0]+ln_b[0];
    float xn1 = d1*inv*ln_g[1]+ln_b[1];
    float xn2 = d2*inv*ln_g[2]+ln_b[2];
    float xn3 = d3*inv*ln_g[3]+ln_b[3];

    float s1[64];
    #pragma unroll
    for (int j = 0; j < 64; ++j) {
        float a = b1[j];
        a = fmaf(xn0, w1[j],       a);
        a = fmaf(xn1, w1[64 + j],  a);
        a = fmaf(xn2, w1[128 + j], a);
        a = fmaf(xn3, w1[192 + j], a);
        s1[j] = fmaxf(a, 0.f);
    }
    #pragma unroll
    for (int j = 0; j < 32; j += 8) {
        float4 f0 = *(const float4*)(feats + (size_t)p*32 + j);
        float4 f1 = *(const float4*)(feats + (size_t)p*32 + j + 4);
        uint4 u = make_uint4(pk2(f0.x,f0.y), pk2(f0.z,f0.w),
                             pk2(f1.x,f1.y), pk2(f1.z,f1.w));
        *(uint4*)(out + j) = u;
    }
    for (int j0 = 0; j0 < 64; j0 += 8) {
        float a[8];
        #pragma unroll
        for (int i = 0; i < 8; ++i) a[i] = b2[j0+i];
        #pragma unroll
        for (int k = 0; k < 64; ++k) {
            float s = s1[k];
            const float* wr = &w2[k*64 + j0];
            #pragma unroll
            for (int i = 0; i < 8; ++i) a[i] = fmaf(s, wr[i], a[i]);
        }
        #pragma unroll
        for (int i = 0; i < 8; ++i) a[i] = fmaxf(a[i], 0.f);
        uint4 u = make_uint4(pk2(a[0],a[1]), pk2(a[2],a[3]),
                             pk2(a[4],a[5]), pk2(a[6],a[7]));
        *(uint4*)(out + 32 + j0) = u;
    }
    uint4 z = make_uint4(0,0,0,0);
    *(uint4*)(out + 96)  = z;
    *(uint4*)(out + 104) = z;
    *(uint4*)(out + 112) = z;
    *(uint4*)(out + 120) = z;
}

// ---------------------------------------------------------------------------
// Per-point front-end, FP32 output, gather variant (rescore pass)
// ---------------------------------------------------------------------------
__global__ __launch_bounds__(256) void k_x96f(
    const float* __restrict__ coords, const float* __restrict__ feats,
    const float* __restrict__ times,
    const float* __restrict__ ln_g, const float* __restrict__ ln_b,
    const float* __restrict__ sw1, const float* __restrict__ sb1,
    const float* __restrict__ sw2, const float* __restrict__ sb2,
    const int* __restrict__ sel, int M, float* __restrict__ X96)
{
    __shared__ float w1[256], w2[4096], b1[64], b2[64];
    int t = threadIdx.x;
    w1[t] = sw1[t];
    for (int i = t; i < 4096; i += 256) w2[i] = sw2[i];
    if (t < 64) { b1[t] = sb1[t]; b2[t] = sb2[t]; }
    __syncthreads();

    int r = blockIdx.x * 256 + t;
    if (r >= M) return;
    int p = sel[r];
    float* out = X96 + (size_t)r * 96;
    if (p < 0) {
        for (int j = 0; j < 96; j += 4) *(float4*)(out + j) = make_float4(0.f,0.f,0.f,0.f);
        return;
    }
    float x0 = coords[(size_t)p*3+0], x1 = coords[(size_t)p*3+1];
    float x2 = coords[(size_t)p*3+2], x3 = times[p];
    float mu = 0.25f*(x0+x1+x2+x3);
    float d0 = x0-mu, d1 = x1-mu, d2 = x2-mu, d3 = x3-mu;
    float var = 0.25f*(d0*d0+d1*d1+d2*d2+d3*d3);
    float inv = 1.0f / sqrtf(var + 1e-5f);
    float xn0 = d0*inv*ln_g[0]+ln_b[0];
    float xn1 = d1*inv*ln_g[1]+ln_b[1];
    float xn2 = d2*inv*ln_g[2]+ln_b[2];
    float xn3 = d3*inv*ln_g[3]+ln_b[3];

    float s1[64];
    #pragma unroll
    for (int j = 0; j < 64; ++j) {
        float a = b1[j];
        a = fmaf(xn0, w1[j],       a);
        a = fmaf(xn1, w1[64 + j],  a);
        a = fmaf(xn2, w1[128 + j], a);
        a = fmaf(xn3, w1[192 + j], a);
        s1[j] = fmaxf(a, 0.f);
    }
    #pragma unroll
    for (int j = 0; j < 32; j += 4)
        *(float4*)(out + j) = *(const float4*)(feats + (size_t)p*32 + j);

    for (int j0 = 0; j0 < 64; j0 += 4) {
        float a0 = b2[j0+0], a1 = b2[j0+1], a2 = b2[j0+2], a3 = b2[j0+3];
        #pragma unroll
        for (int k = 0; k < 64; ++k) {
            float s = s1[k];
            const float* wr = &w2[k*64 + j0];
            a0 = fmaf(s, wr[0], a0);
            a1 = fmaf(s, wr[1], a1);
            a2 = fmaf(s, wr[2], a2);
            a3 = fmaf(s, wr[3], a3);
        }
        *(float4*)(out + 32 + j0) =
            make_float4(fmaxf(a0,0.f), fmaxf(a1,0.f), fmaxf(a2,0.f), fmaxf(a3,0.f));
    }
}

// ---------------------------------------------------------------------------
// Pure-f16 MFMA GEMM (scoring): O = act(A[M][K] @ Bt[N][K]^T + b), f16 out.
// m97-style: global_load_lds(16B) direct staging, linear LDS dest,
// pre-swizzled global source, XOR-swizzled ds_read_b128.
// LDS(r, j) = G(r, j ^ (r&7)); reader XORs back. 128x128x64 tile, 4 waves.
// ---------------------------------------------------------------------------
__global__ __launch_bounds__(256, 2) void k_hgemm(
    const unsigned short* __restrict__ A, const unsigned short* __restrict__ Bt,
    const float* __restrict__ bias, unsigned short* __restrict__ O,
    int M, int K, int N, int relu)
{
    __shared__ unsigned short sA[128*64];   // 16 KiB, swizzled content
    __shared__ unsigned short sB[128*64];
    const int tid = threadIdx.x;
    const int bm = blockIdx.y, bn = blockIdx.x;
    const int lane = tid & 63, w = tid >> 6;
    const int wm = w >> 1, wn = w & 1;
    const int lr = lane & 15, lg = lane >> 4;

    // staging: wave w covers rows [w*32, w*32+32) of A and B (4 chunks of 8 rows).
    // lane -> row-in-chunk (lane>>3), LDS block (lane&7); global source block
    // pre-swizzled so linear LDS write lands swizzled content.
    const int srow = lane >> 3;                 // 0..7 == r&7 (chunk base % 8 == 0)
    const int sblk = (lane & 7) ^ srow;
    const unsigned short* ga0 = A  + ((size_t)(bm*128 + w*32 + srow)) * K + sblk*8;
    const unsigned short* gb0 = Bt + ((size_t)(bn*128 + w*32 + srow)) * K + sblk*8;

    f32x4 acc[4][4];
    #pragma unroll
    for (int m = 0; m < 4; ++m)
        #pragma unroll
        for (int n = 0; n < 4; ++n) acc[m][n] = (f32x4){0.f,0.f,0.f,0.f};

    for (int kt = 0; kt < K; kt += 64) {
        #pragma unroll
        for (int i = 0; i < 4; ++i) {
            gload16(ga0 + kt + (size_t)(i*8)*K, sA + (w*32 + i*8)*64);
            gload16(gb0 + kt + (size_t)(i*8)*K, sB + (w*32 + i*8)*64);
        }
        __syncthreads();                 // drains vmcnt -> tiles visible

        #pragma unroll
        for (int kk = 0; kk < 64; kk += 32) {
            const int jj = lg + (kk >> 3);          // k-block 0..7
            f16x8 af[4], bf[4];
            #pragma unroll
            for (int m = 0; m < 4; ++m) {
                int r = wm*64 + m*16 + lr;
                af[m] = *(const f16x8*)&sA[r*64 + ((jj ^ (r & 7)) << 3)];
            }
            #pragma unroll
            for (int n = 0; n < 4; ++n) {
                int r = wn*64 + n*16 + lr;
                bf[n] = *(const f16x8*)&sB[r*64 + ((jj ^ (r & 7)) << 3)];
            }
            #pragma unroll
            for (int m = 0; m < 4; ++m)
                #pragma unroll
                for (int n = 0; n < 4; ++n)
                    acc[m][n] = __builtin_amdgcn_mfma_f32_16x16x32_f16(af[m], bf[n], acc[m][n], 0, 0, 0);
        }
        __syncthreads();                 // before next overwrite
    }

    #pragma unroll
    for (int n = 0; n < 4; ++n) {
        int col = bn*128 + wn*64 + n*16 + lr;
        float bb = bias[col];
        #pragma unroll
        for (int m = 0; m < 4; ++m) {
            int row0 = bm*128 + wm*64 + m*16 + lg*4;
            #pragma unroll
            for (int q = 0; q < 4; ++q) {
                float v = acc[m][n][q] + bb;
                if (relu) v = fmaxf(v, 0.f);
                f16 h = (f16)v;
                O[(size_t)(row0 + q) * N + col] = __builtin_bit_cast(unsigned short, h);
            }
        }
    }
}

// ---------------------------------------------------------------------------
// fp32 GEMM (rescore pass). Column split {tc*4, 64+tc*4} -> conflict-free B reads.
// ---------------------------------------------------------------------------
#define BM 128
#define BN 128
#define BK 16

__global__ __launch_bounds__(256) void k_gemm(
    const float* __restrict__ A, const float* __restrict__ W,
    const float* __restrict__ bias, float* __restrict__ C,
    int M, int K, int Nn, int relu)
{
    __shared__ float As[BK][BM + 4];
    __shared__ float Bs[BK][BN];
    const int tid = threadIdx.x;
    const int bm = blockIdx.y, bn = blockIdx.x;
    const int tr = tid >> 4, tc = tid & 15;
    const int ar0 = tid >> 2, ac0 = (tid & 3) * 4;
    const int bk0 = tid >> 5, bn0 = (tid & 31) * 4;
    const float* Ab = A + (size_t)bm * BM * K;
    const float* Wb = W + (size_t)bn * BN;

    float acc[8][8];
    #pragma unroll
    for (int i = 0; i < 8; ++i)
        #pragma unroll
        for (int j = 0; j < 8; ++j) acc[i][j] = 0.f;

    for (int k0 = 0; k0 < K; k0 += BK) {
        float4 a0 = *(const float4*)(Ab + (size_t)ar0*K      + k0 + ac0);
        float4 a1 = *(const float4*)(Ab + (size_t)(ar0+64)*K + k0 + ac0);
        float4 w0 = *(const float4*)(Wb + (size_t)(k0+bk0  )*Nn + bn0);
        float4 w1 = *(const float4*)(Wb + (size_t)(k0+bk0+8)*Nn + bn0);
        As[ac0+0][ar0]    = a0.x; As[ac0+1][ar0]    = a0.y;
        As[ac0+2][ar0]    = a0.z; As[ac0+3][ar0]    = a0.w;
        As[ac0+0][ar0+64] = a1.x; As[ac0+1][ar0+64] = a1.y;
        As[ac0+2][ar0+64] = a1.z; As[ac0+3][ar0+64] = a1.w;
        *(float4*)&Bs[bk0  ][bn0] = w0;
        *(float4*)&Bs[bk0+8][bn0] = w1;
        __syncthreads();
        #pragma unroll
        for (int kk = 0; kk < BK; ++kk) {
            float4 av0 = *(const float4*)&As[kk][tr*8];
            float4 av1 = *(const float4*)&As[kk][tr*8+4];
            float4 bv0 = *(const float4*)&Bs[kk][tc*4];        // blocks tc   (consecutive)
            float4 bv1 = *(const float4*)&Bs[kk][64 + tc*4];   // blocks 16+tc
            float a[8] = {av0.x,av0.y,av0.z,av0.w, av1.x,av1.y,av1.z,av1.w};
            float b[8] = {bv0.x,bv0.y,bv0.z,bv0.w, bv1.x,bv1.y,bv1.z,bv1.w};
            #pragma unroll
            for (int i = 0; i < 8; ++i)
                #pragma unroll
                for (int j = 0; j < 8; ++j)
                    acc[i][j] = fmaf(a[i], b[j], acc[i][j]);
        }
        __syncthreads();
    }

    float bl[8];
    #pragma unroll
    for (int j = 0; j < 4; ++j) {
        bl[j]   = bias[(size_t)bn*BN + tc*4 + j];
        bl[j+4] = bias[(size_t)bn*BN + 64 + tc*4 + j];
    }
    #pragma unroll
    for (int i = 0; i < 8; ++i) {
        int row = bm*BM + tr*8 + i;
        float v[8];
        #pragma unroll
        for (int j = 0; j < 8; ++j) {
            float x = acc[i][j] + bl[j];
            v[j] = relu ? fmaxf(x, 0.f) : x;
        }
        float* cr = C + (size_t)row*Nn + bn*BN;
        *(float4*)(cr + tc*4)      = make_float4(v[0],v[1],v[2],v[3]);
        *(float4*)(cr + 64 + tc*4) = make_float4(v[4],v[5],v[6],v[7]);
    }
}

// ---------------------------------------------------------------------------
// scores from f16 T4 (stage 1) and fp32 T4 (rescore)
// ---------------------------------------------------------------------------
__global__ __launch_bounds__(256) void k_scoreh(
    const unsigned short* __restrict__ T4, const float* __restrict__ hw2,
    const float* __restrict__ hb2, float* __restrict__ scores, int M)
{
    int wv = (blockIdx.x * 256 + threadIdx.x) >> 6;
    int lane = threadIdx.x & 63;
    if (wv >= M) return;
    const unsigned short* row = T4 + (size_t)wv * 384;
    float s = 0.f;
    #pragma unroll
    for (int j = 0; j < 384; j += 64) {
        f16 h = __builtin_bit_cast(f16, row[j + lane]);
        s = fmaf((float)h, hw2[j + lane], s);
    }
    for (int o = 32; o > 0; o >>= 1) s += __shfl_down(s, o, 64);
    if (lane == 0) scores[wv] = s + hb2[0];
}

__global__ __launch_bounds__(256) void k_score(
    const float* __restrict__ T4, const float* __restrict__ hw2,
    const float* __restrict__ hb2, float* __restrict__ scores, int M)
{
    int wv = (blockIdx.x * 256 + threadIdx.x) >> 6;
    int lane = threadIdx.x & 63;
    if (wv >= M) return;
    const float* row = T4 + (size_t)wv * 384;
    float s = 0.f;
    #pragma unroll
    for (int j = 0; j < 384; j += 64) s = fmaf(row[j + lane], hw2[j + lane], s);
    for (int o = 32; o > 0; o >>= 1) s += __shfl_down(s, o, 64);
    if (lane == 0) scores[wv] = s + hb2[0];
}

// ---------------------------------------------------------------------------
// Stage 1 select: per-batch top-CAND via bitonic sort.
// Key: [sortable(score):32][~pos:32]  => value desc, pos asc.
// ---------------------------------------------------------------------------
#define TPAD 4096
__global__ __launch_bounds__(256) void k_topcand(
    const float* __restrict__ scores, const int* __restrict__ offs,
    int* __restrict__ cand_g, int* __restrict__ cand_p)
{
    __shared__ uint64_t key[TPAD];   // 32 KiB
    int b = blockIdx.x, t = threadIdx.x;
    int off = offs[b];
    int cnt = min(offs[b+1] - off, MAXPB);

    for (int i = t; i < TPAD; i += 256) {
        uint64_t k = 0;
        if (i < cnt)
            k = ((uint64_t)sortable(scores[off + i]) << 32) | (uint32_t)(~i);
        key[i] = k;
    }

    for (int ksz = 2; ksz <= TPAD; ksz <<= 1) {
        for (int j = ksz >> 1; j > 0; j >>= 1) {
            __syncthreads();
            for (int i = t; i < TPAD; i += 256) {
                int ix = i ^ j;
                if (ix > i) {
                    uint64_t a = key[i], c = key[ix];
                    bool up = (i & ksz) == 0;
                    if (up ? (a < c) : (a > c)) { key[i] = c; key[ix] = a; }
                }
            }
        }
    }
    __syncthreads();

    if (t < CAND) {
        if (t < cnt) {
            int pos = (int)(~(uint32_t)key[t]);
            cand_g[b*CAND + t] = off + pos;
            cand_p[b*CAND + t] = pos;
        } else {
            cand_g[b*CAND + t] = -1;
            cand_p[b*CAND + t] = MAXPB + t;
        }
    }
}

// ---------------------------------------------------------------------------
// Stage 2: final top-MT by fp32 score via bitonic.
// Key: [sortable(fscore):32][~pos:12][j:8]
// ---------------------------------------------------------------------------
__global__ __launch_bounds__(256) void k_fsel(
    const float* __restrict__ fscores, const int* __restrict__ offs,
    const int* __restrict__ cand_g, const int* __restrict__ cand_p,
    const float* __restrict__ coords, const float* __restrict__ times,
    int* __restrict__ tok_src, float* __restrict__ out_cent,
    float* __restrict__ out_mask)
{
    __shared__ uint64_t key[256];
    int b = blockIdx.x, t = threadIdx.x;
    int cnt = min(offs[b+1] - offs[b], MAXPB);
    int cntc = min(cnt, CAND);

    uint64_t k = 0;
    if (t < cntc) {
        uint32_t s32 = sortable(fscores[b*CAND + t]);
        uint32_t pos = (uint32_t)cand_p[b*CAND + t];
        k = ((uint64_t)s32 << 32) | (((~pos) & 0xFFFu) << 8) | (uint32_t)t;
    }
    key[t] = k;

    for (int ksz = 2; ksz <= 256; ksz <<= 1) {
        for (int j = ksz >> 1; j > 0; j >>= 1) {
            __syncthreads();
            int ix = t ^ j;
            if (ix > t) {
                uint64_t a = key[t], c = key[ix];
                bool up = (t & ksz) == 0;
                if (up ? (a < c) : (a > c)) { key[t] = c; key[ix] = a; }
            }
        }
    }
    __syncthreads();

    if (t < MT) {
        if (t < cntc) {
            int j = (int)(key[t] & 0xFF);
            int row = b*CAND + j;
            int g = cand_g[row];
            tok_src[b*MT + t] = row;
            out_mask[b*MT + t] = 1.0f;
            *(float4*)&out_cent[(size_t)(b*MT + t) * 4] =
                make_float4(coords[(size_t)g*3+0], coords[(size_t)g*3+1],
                            coords[(size_t)g*3+2], times[g]);
        } else {
            tok_src[b*MT + t] = -1;
            out_mask[b*MT + t] = 0.0f;
            *(float4*)&out_cent[(size_t)(b*MT + t) * 4] = make_float4(0.f,0.f,0.f,0.f);
        }
    }
}

// gather tokens from candidate point_feats
__global__ __launch_bounds__(256) void k_tokens(const float* __restrict__ PFc,
                                                const int* __restrict__ tok_src,
                                                float* __restrict__ out)
{
    int i = blockIdx.x * 256 + threadIdx.x;   // 8192*192 float4
    int row = i / 192, c = i % 192;
    int src = tok_src[row];
    float4 v = make_float4(0.f,0.f,0.f,0.f);
    if (src >= 0) v = ((const float4*)PFc)[(size_t)src*192 + c];
    ((float4*)out)[(size_t)row*192 + c] = v;
}

// ---------------------------------------------------------------------------
extern "C" void kernel_launch(void* const* d_in, const int* in_sizes, int n_in,
                              void* d_out, int out_size, void* d_ws, size_t ws_size,
                              hipStream_t stream)
{
    const float* coords = (const float*)d_in[0];
    const float* feats  = (const float*)d_in[1];
    const float* times  = (const float*)d_in[2];
    const int*   bids   = (const int*)  d_in[3];
    const float* ln_g = (const float*)d_in[4];
    const float* ln_b = (const float*)d_in[5];
    const float* sw1  = (const float*)d_in[6];
    const float* sb1  = (const float*)d_in[7];
    const float* sw2  = (const float*)d_in[8];
    const float* sb2  = (const float*)d_in[9];
    const float* mw1  = (const float*)d_in[10];
    const float* mb1  = (const float*)d_in[11];
    const float* mw2  = (const float*)d_in[12];
    const float* mb2  = (const float*)d_in[13];
    const float* mw3  = (const float*)d_in[14];
    const float* mb3  = (const float*)d_in[15];
    const float* mw4  = (const float*)d_in[16];
    const float* mb4  = (const float*)d_in[17];
    const float* hw1  = (const float*)d_in[18];
    const float* hb1  = (const float*)d_in[19];
    const float* hw2  = (const float*)d_in[20];
    const float* hb2  = (const float*)d_in[21];

    float* out_tok  = (float*)d_out;
    float* out_cent = out_tok + (size_t)NB*MT*TD;
    float* out_mask = out_cent + (size_t)NB*MT*4;

    char* wsb = (char*)d_ws;
    size_t off = 0;
    auto alloc = [&](size_t bytes) {
        char* p = wsb + off;
        off = (off + bytes + 255) & ~(size_t)255;
        return p;
    };
    auto mx = [](size_t a, size_t b) { return a > b ? a : b; };

    int*   offs    = (int*)  alloc((NB + 1) * 4);
    float* scores  = (float*)alloc((size_t)NPTS * 4);
    float* fscores = (float*)alloc((size_t)MC * 4);
    int*   cand_g  = (int*)  alloc((size_t)MC * 4);
    int*   cand_p  = (int*)  alloc((size_t)MC * 4);
    int*   tok_src = (int*)  alloc((size_t)NB * MT * 4);
    unsigned short* wt1h = (unsigned short*)alloc((size_t)256 * 128 * 2);
    unsigned short* wt2h = (unsigned short*)alloc((size_t)512 * 256 * 2);
    unsigned short* wt3h = (unsigned short*)alloc((size_t)768 * 512 * 2);
    unsigned short* wt4h = (unsigned short*)alloc((size_t)768 * 768 * 2);
    unsigned short* ht1h = (unsigned short*)alloc((size_t)384 * 768 * 2);
    size_t base = off;

    int Nc = 8192;
    const int cands[3] = {32768, 16384, 8192};
    for (int ci = 0; ci < 3; ++ci) {
        size_t n = cands[ci];
        size_t need = base
            + mx(n*128*2, (size_t)MC*96*4)
            + mx(n*256*2, (size_t)MC*256*4)
            + mx(n*512*2, (size_t)MC*512*4)
            + 2 * mx(n*768*2, (size_t)MC*768*4)
            + 6*256;
        if (need <= ws_size) { Nc = (int)n; break; }
    }
    char* B0 = alloc(mx((size_t)Nc*128*2, (size_t)MC*96*4));
    char* B1 = alloc(mx((size_t)Nc*256*2, (size_t)MC*256*4));
    char* B2 = alloc(mx((size_t)Nc*512*2, (size_t)MC*512*4));
    char* B3 = alloc(mx((size_t)Nc*768*2, (size_t)MC*768*4));
    char* B4 = alloc(mx((size_t)Nc*768*2, (size_t)MC*768*4));

    // ---------- setup ----------
    k_counts<<<1, 128, 0, stream>>>(bids, offs);
    k_cvtw<<<(256*128+255)/256, 256, 0, stream>>>(mw1, wt1h,  96, 256, 128);
    k_cvtw<<<(512*256+255)/256, 256, 0, stream>>>(mw2, wt2h, 256, 512, 256);
    k_cvtw<<<(768*512+255)/256, 256, 0, stream>>>(mw3, wt3h, 512, 768, 512);
    k_cvtw<<<(768*768+255)/256, 256, 0, stream>>>(mw4, wt4h, 768, 768, 768);
    k_cvtw<<<(384*768+255)/256, 256, 0, stream>>>(hw1, ht1h, 768, 384, 768);

    // ---------- stage 1: pure-f16 MFMA scoring over all points ----------
    {
        unsigned short* X   = (unsigned short*)B0;   // [Nc][128]
        unsigned short* H1h = (unsigned short*)B1;   // [Nc][256]
        unsigned short* H2h = (unsigned short*)B2;   // [Nc][512]
        unsigned short* H3h = (unsigned short*)B3;   // [Nc][768]
        unsigned short* PFh = (unsigned short*)B4;   // [Nc][768]
        unsigned short* T4h = (unsigned short*)B2;   // [Nc][384], H2 dead by then
        for (int p0 = 0; p0 < NPTS; p0 += Nc) {
            int Mi = min(Nc, NPTS - p0);
            k_x96h<<<(Mi+255)/256, 256, 0, stream>>>(coords, feats, times, ln_g, ln_b,
                                                     sw1, sb1, sw2, sb2, p0, Mi, X);
            k_hgemm<<<dim3(2, Mi/128), 256, 0, stream>>>(X,   wt1h, mb1, H1h, Mi, 128, 256, 1);
            k_hgemm<<<dim3(4, Mi/128), 256, 0, stream>>>(H1h, wt2h, mb2, H2h, Mi, 256, 512, 1);
            k_hgemm<<<dim3(6, Mi/128), 256, 0, stream>>>(H2h, wt3h, mb3, H3h, Mi, 512, 768, 1);
            k_hgemm<<<dim3(6, Mi/128), 256, 0, stream>>>(H3h, wt4h, mb4, PFh, Mi, 768, 768, 0);
            k_hgemm<<<dim3(3, Mi/128), 256, 0, stream>>>(PFh, ht1h, hb1, T4h, Mi, 768, 384, 1);
            k_scoreh<<<(Mi+3)/4, 256, 0, stream>>>(T4h, hw2, hb2, scores + p0, Mi);
        }
    }

    // ---------- stage 2: capture top-CAND per batch (bitonic) ----------
    k_topcand<<<NB, 256, 0, stream>>>(scores, offs, cand_g, cand_p);

    // ---------- stage 3: fp32 rescore of candidates ----------
    {
        float* X96 = (float*)B0;
        float* H1  = (float*)B1;
        float* H2  = (float*)B2;
        float* H3  = (float*)B3;
        float* PFc = (float*)B4;
        float* T4  = (float*)B2;           // H2 dead by head time
        k_x96f<<<MC/256, 256, 0, stream>>>(coords, feats, times, ln_g, ln_b,
                                           sw1, sb1, sw2, sb2, cand_g, MC, X96);
        k_gemm<<<dim3(2, MC/128), 256, 0, stream>>>(X96, mw1, mb1, H1, MC,  96, 256, 1);
        k_gemm<<<dim3(4, MC/128), 256, 0, stream>>>(H1,  mw2, mb2, H2, MC, 256, 512, 1);
        k_gemm<<<dim3(6, MC/128), 256, 0, stream>>>(H2,  mw3, mb3, H3, MC, 512, 768, 1);
        k_gemm<<<dim3(6, MC/128), 256, 0, stream>>>(H3,  mw4, mb4, PFc, MC, 768, 768, 0);
        k_gemm<<<dim3(3, MC/128), 256, 0, stream>>>(PFc, hw1, hb1, T4, MC, 768, 384, 1);
        k_score<<<MC/4, 256, 0, stream>>>(T4, hw2, hb2, fscores, MC);

        // ---------- stage 4: final top-128 per batch (bitonic) ----------
        k_fsel<<<NB, 256, 0, stream>>>(fscores, offs, cand_g, cand_p,
                                       coords, times, tok_src, out_cent, out_mask);
        k_tokens<<<(NB*MT*192)/256, 256, 0, stream>>>(PFc, tok_src, out_tok);
    }
}